// Round 8
// baseline (924.679 us; speedup 1.0000x reference)
//
#include <hip/hip_runtime.h>
#include <math.h>
#include <float.h>

#define DEV __device__ __forceinline__

#define BB 8
#define TT 24000
#define TD 23989
#define NZ 2000
#define ROWS 16000
#define NE 8192
#define NCG 8

typedef __attribute__((ext_vector_type(8))) short bf16x8;
typedef __attribute__((ext_vector_type(4))) float f32x4;

// ---------------- static device storage ----------------
__device__ double g_st[640];
__device__ double g_misc[2];
__device__ float  g_e2[NE];
__device__ float  g_avg[NE];
__device__ float  g_z2[ROWS];
__device__ float  g_rdm[ROWS];
__device__ int    g_rix[ROWS];
__device__ float  g_ob[256 * 64];
__device__ float  g_pmd[ROWS * NCG];
__device__ int    g_pmi[ROWS * NCG];
__device__ int    g_pcc[ROWS * NCG];
__device__ float2 g_cand[ROWS * 256];
__device__ unsigned short g_zbh[ROWS * 64], g_zbl[ROWS * 64];
__device__ unsigned short g_ebh[NE * 64],  g_ebl[NE * 64];
__device__ float  g_s1[16], g_sh1[16];
__device__ float  g_s2[32], g_sh2[32];
__device__ float  g_sd1[64], g_shd1[64];
__device__ float  g_w2f[2560];
__device__ float  g_b2f[32];
__device__ float  g_w3f[64 * 32 * 25];
__device__ float  g_b3f[64];
__device__ unsigned short g_dwh[5 * 2 * 64 * 32];   // dconv2 W hi-bf16, MFMA fragment order
__device__ unsigned short g_dwl[5 * 2 * 64 * 32];   // dconv2 W lo-bf16
__device__ float  g_db2f[64];
__device__ float  g_dw1t[64 * 64 * 25];
__device__ float  g_zbn[ROWS * 64];
__device__ double g_zbnd[ROWS * 64];
__device__ float  g_zq[BB * 64 * NZ];
__device__ float  g_y1[BB * 16 * TT];
__device__ float  g_zpre[BB * 64 * NZ];
__device__ float  g_yd1[BB * 64 * TD];
__device__ float  g_y2[BB * 32 * TT];
__device__ float  g_yd2[BB * 64 * TD];

DEV float wsum(float v){
  #pragma unroll
  for (int o = 32; o; o >>= 1) v += __shfl_xor(v, o, 64);
  return v;
}
DEV int clampc(int c){ return c < 0 ? 0 : (c > NE - 1 ? NE - 1 : c); }
DEV float bss(unsigned short s){ union { unsigned u; float f; } v; v.u = ((unsigned)s) << 16; return v.f; }
DEV unsigned short f2bs(float f){
  union { float f; unsigned u; } v; v.f = f;
  unsigned r = (v.u + 0x7FFF + ((v.u >> 16) & 1)) >> 16;
  return (unsigned short)r;
}

__global__ void k_zero(){
  int i = blockIdx.x * 256 + threadIdx.x;
  if (i < 640) g_st[i] = 0.0;
  if (i < 2) g_misc[i] = 0.0;
  if (i < NE) g_avg[i] = 0.f;
}

// ---------------- embed prep: |e|^2 + bf16 split ----------------
__global__ void k_embprep(const float* __restrict__ embed){
  int gt = blockIdx.x * 256 + threadIdx.x;
  int gs = gridDim.x * 256;
  for (int i = gt; i < NE * 64; i += gs){
    float v = embed[i];
    unsigned short h = f2bs(v);
    g_ebh[i] = h;
    g_ebl[i] = f2bs(v - bss(h));
  }
  for (int c = gt; c < NE; c += gs){
    float s = 0.f;
    for (int j = 0; j < 64; j++){ float v = embed[c * 64 + j]; s += v * v; }
    g_e2[c] = s;
  }
}

// ---------------- z bf16 split (after zbn) ----------------
__global__ void k_zsplit(){
  int i = blockIdx.x * 256 + threadIdx.x;
  if (i < ROWS * 64){
    float v = g_zbn[i];
    unsigned short h = f2bs(v);
    g_zbh[i] = h;
    g_zbl[i] = f2bs(v - bss(h));
  }
}

// ---------------- conv1: silu + stats ----------------
__global__ void k_conv1(const float* __restrict__ x, const float* __restrict__ w1,
                        const float* __restrict__ b1){
  int b = blockIdx.y, t0 = blockIdx.x * 256, tid = threadIdx.x;
  __shared__ float xs[260], wl[80], bl[16], sacc[16], qacc[16];
  if (tid < 80) wl[tid] = w1[tid];
  if (tid < 16){ bl[tid] = b1[tid]; sacc[tid] = 0.f; qacc[tid] = 0.f; }
  for (int i = tid; i < 260; i += 256){ int g = t0 - 2 + i; xs[i] = ((unsigned)g < TT) ? x[b * TT + g] : 0.f; }
  __syncthreads();
  int t = t0 + tid;
  bool ok = t < TT;
  float xv[5];
  #pragma unroll
  for (int k = 0; k < 5; k++) xv[k] = xs[tid + k];
  float out[16];
  #pragma unroll
  for (int c = 0; c < 16; c++){
    float a = bl[c];
    #pragma unroll
    for (int k = 0; k < 5; k++) a += wl[c * 5 + k] * xv[k];
    float o = ok ? a / (1.f + expf(-a)) : 0.f;
    out[c] = o;
    if (ok) g_y1[(b * 16 + c) * TT + t] = o;
  }
  int lane = tid & 63;
  #pragma unroll
  for (int c = 0; c < 16; c++){
    float s = wsum(out[c]);
    float q = wsum(out[c] * out[c]);
    if (lane == 0){ atomicAdd(&sacc[c], s); atomicAdd(&qacc[c], q); }
  }
  __syncthreads();
  if (tid < 16){ atomicAdd(&g_st[tid * 2], (double)sacc[tid]); atomicAdd(&g_st[tid * 2 + 1], (double)qacc[tid]); }
}

// ---------------- bn1 factors + raw w2 transpose ----------------
__global__ void k_fold2(const float* __restrict__ g1, const float* __restrict__ be1,
                        const float* __restrict__ w2, const float* __restrict__ b2){
  int tid = threadIdx.x;
  if (blockIdx.x == 0 && tid < 16){
    double m = g_st[tid * 2] / 192000.0, v = g_st[tid * 2 + 1] / 192000.0 - m * m;
    float s = g1[tid] / sqrtf((float)v + 1e-5f);
    g_s1[tid] = s; g_sh1[tid] = be1[tid] - (float)m * s;
  }
  if (blockIdx.x == 0 && tid < 32) g_b2f[tid] = b2[tid];
  int gt = blockIdx.x * 256 + tid;
  for (int i = gt; i < 2560; i += 8 * 256){
    int co = i & 31, r = i >> 5, k = r % 5, ci = r / 5;
    g_w2f[i] = w2[(co * 16 + ci) * 5 + k];
  }
}

// ---------------- conv2: 8co/wave x 4t/lane, BN at stage-in, silu, stats ----------------
__global__ void __launch_bounds__(256) k_conv2(){
  int b = blockIdx.y, t0 = blockIdx.x * 256, tid = threadIdx.x;
  __shared__ float xs[16][260];
  __shared__ float sacc[32], qacc[32];
  __shared__ float s1l[16], sh1l[16];
  int lane = tid & 63, wv = tid >> 6;
  int cb = wv * 8;
  if (tid < 32){ sacc[tid] = 0.f; qacc[tid] = 0.f; }
  if (tid < 16){ s1l[tid] = g_s1[tid]; sh1l[tid] = g_sh1[tid]; }
  __syncthreads();
  for (int i = tid; i < 16 * 260; i += 256){
    int ci = i / 260, tt = i - ci * 260, g = t0 - 2 + tt;
    xs[ci][tt] = ((unsigned)g < TT) ? (s1l[ci] * g_y1[(b * 16 + ci) * TT + g] + sh1l[ci]) : 0.f;
  }
  __syncthreads();
  float acc[4][8];
  #pragma unroll
  for (int j = 0; j < 4; j++)
    #pragma unroll
    for (int i = 0; i < 8; i++) acc[j][i] = g_b2f[cb + i];
  for (int ci = 0; ci < 16; ci++){
    #pragma unroll
    for (int k = 0; k < 5; k++){
      const float4* wp = (const float4*)(g_w2f + (ci * 5 + k) * 32 + cb);
      float4 w0 = wp[0], w1v = wp[1];
      float wr[8] = { w0.x, w0.y, w0.z, w0.w, w1v.x, w1v.y, w1v.z, w1v.w };
      #pragma unroll
      for (int j = 0; j < 4; j++){
        float xv = xs[ci][lane + 64 * j + k];
        #pragma unroll
        for (int i = 0; i < 8; i++) acc[j][i] += wr[i] * xv;
      }
    }
  }
  #pragma unroll
  for (int i = 0; i < 8; i++){
    int co = cb + i;
    float s = 0.f, q = 0.f;
    #pragma unroll
    for (int j = 0; j < 4; j++){
      int t = t0 + lane + 64 * j;
      bool ok = t < TT;
      float a = acc[j][i];
      float o = ok ? a / (1.f + expf(-a)) : 0.f;
      if (ok) g_y2[(b * 32 + co) * TT + t] = o;
      s += o; q += o * o;
    }
    s = wsum(s); q = wsum(q);
    if (lane == 0){ atomicAdd(&sacc[co], s); atomicAdd(&qacc[co], q); }
  }
  __syncthreads();
  if (tid < 32){ atomicAdd(&g_st[128 + tid * 2], (double)sacc[tid]); atomicAdd(&g_st[128 + tid * 2 + 1], (double)qacc[tid]); }
}

// ---------------- bn2 factors + raw w3 transpose ----------------
__global__ void k_fold3(const float* __restrict__ g2, const float* __restrict__ be2,
                        const float* __restrict__ w3, const float* __restrict__ b3){
  int tid = threadIdx.x;
  if (blockIdx.x == 0 && tid < 32){
    double m = g_st[128 + tid * 2] / 192000.0, v = g_st[128 + tid * 2 + 1] / 192000.0 - m * m;
    float s = g2[tid] / sqrtf((float)v + 1e-5f);
    g_s2[tid] = s; g_sh2[tid] = be2[tid] - (float)m * s;
  }
  if (blockIdx.x == 0 && tid >= 64 && tid < 128) g_b3f[tid - 64] = b3[tid - 64];
  int gt = blockIdx.x * 256 + tid;
  for (int i = gt; i < 64 * 32 * 25; i += 64 * 256){
    int co = i & 63, r = i >> 6, k = r % 25, ci = r / 25;
    g_w3f[i] = w3[(co * 32 + ci) * 25 + k];
  }
}

// ---------------- conv3: 16co/wave, lane=(t32,ci-half), shfl reduce, tanh ----------------
__global__ void __launch_bounds__(256) k_conv3(){
  __shared__ float xs[32][400];
  __shared__ float s2l[32], sh2l[32];
  int tid = threadIdx.x, b = blockIdx.y, t0 = blockIdx.x * 32;
  int lane = tid & 63, wv = tid >> 6;
  int cb = wv * 16;
  int tl = lane & 31, h = lane >> 5;
  if (tid < 32){ s2l[tid] = g_s2[tid]; sh2l[tid] = g_sh2[tid]; }
  __syncthreads();
  int p0 = t0 * 12 - 12;
  for (int i = tid; i < 32 * 397; i += 256){
    int ci = i / 397, pp = i - ci * 397, g = p0 + pp;
    xs[ci][pp] = ((unsigned)g < TT) ? (s2l[ci] * g_y2[(b * 32 + ci) * TT + g] + sh2l[ci]) : 0.f;
  }
  __syncthreads();
  float acc[16];
  #pragma unroll
  for (int i = 0; i < 16; i++) acc[i] = 0.f;
  for (int cii = 0; cii < 16; cii++){
    int ci = h * 16 + cii;
    #pragma unroll
    for (int k = 0; k < 25; k++){
      float xv = xs[ci][tl * 12 + k];
      const float4* wp = (const float4*)(g_w3f + (ci * 25 + k) * 64 + cb);
      float4 a0 = wp[0], a1 = wp[1], a2 = wp[2], a3 = wp[3];
      acc[0] += a0.x * xv; acc[1] += a0.y * xv; acc[2] += a0.z * xv; acc[3] += a0.w * xv;
      acc[4] += a1.x * xv; acc[5] += a1.y * xv; acc[6] += a1.z * xv; acc[7] += a1.w * xv;
      acc[8] += a2.x * xv; acc[9] += a2.y * xv; acc[10] += a2.z * xv; acc[11] += a2.w * xv;
      acc[12] += a3.x * xv; acc[13] += a3.y * xv; acc[14] += a3.z * xv; acc[15] += a3.w * xv;
    }
  }
  #pragma unroll
  for (int i = 0; i < 16; i++) acc[i] += __shfl_xor(acc[i], 32, 64);
  int t = t0 + tl;
  if (h == 0 && t < NZ){
    #pragma unroll
    for (int i = 0; i < 16; i++)
      g_zpre[(b * 64 + cb + i) * NZ + t] = tanhf(acc[i] + g_b3f[cb + i]);
  }
}

// ---------------- per-channel stats ----------------
__global__ void k_stats(int which, int L, int stoff){
  const float* p = (which == 0) ? g_zpre : (which == 1) ? g_yd1 : g_yd2;
  int co = blockIdx.y, t0 = blockIdx.x * 256, tid = threadIdx.x;
  int t = t0 + tid;
  float s = 0.f, q = 0.f;
  if (t < L){
    for (int b = 0; b < BB; b++){ float v = p[(b * 64 + co) * L + t]; s += v; q += v * v; }
  }
  s = wsum(s); q = wsum(q);
  __shared__ float sa[4], qa[4];
  int w = tid >> 6, lane = tid & 63;
  if (lane == 0){ sa[w] = s; qa[w] = q; }
  __syncthreads();
  if (tid == 0){
    atomicAdd(&g_st[stoff + co * 2], (double)(sa[0] + sa[1] + sa[2] + sa[3]));
    atomicAdd(&g_st[stoff + co * 2 + 1], (double)(qa[0] + qa[1] + qa[2] + qa[3]));
  }
}

// ---------------- bn3 apply + transpose rows + |z|^2 (+f64 copy) ----------------
__global__ void k_zbn(const float* __restrict__ g3, const float* __restrict__ be3){
  __shared__ float tile[64][65];
  __shared__ float s3[64], sh3[64];
  __shared__ double s3d[64], sh3d[64];
  int tid = threadIdx.x, b = blockIdx.y, n0 = blockIdx.x * 64;
  if (tid < 64){
    double m = g_st[256 + tid * 2] / 16000.0, v = g_st[256 + tid * 2 + 1] / 16000.0 - m * m;
    double sd = (double)g3[tid] / sqrt(v + 1e-5);
    double shd = (double)be3[tid] - m * sd;
    s3d[tid] = sd; sh3d[tid] = shd;
    s3[tid] = (float)sd; sh3[tid] = (float)shd;
  }
  __syncthreads();
  for (int i = tid; i < 64 * 64; i += 256){
    int c = i >> 6, nn = i & 63, n = n0 + nn;
    tile[c][nn] = (n < NZ) ? (s3[c] * g_zpre[(b * 64 + c) * NZ + n] + sh3[c]) : 0.f;
  }
  __syncthreads();
  int lane = tid & 63;
  for (int it = 0; it < 16; ++it){
    int nn = (tid >> 6) + it * 4;
    int n = n0 + nn, c = lane;
    if (n < NZ){
      float v = tile[c][nn];
      int row = b * NZ + n;
      g_zbn[row * 64 + c] = v;
      g_zbnd[row * 64 + c] = s3d[c] * (double)g_zpre[(b * 64 + c) * NZ + n] + sh3d[c];
      float s = wsum(v * v);
      if (lane == 0) g_z2[row] = s;
    }
  }
}

// ---------------- VQ pass 1 v3: NO LDS staging -- direct L1/L2 fragment reads, ZERO barriers ----------------
// Round-7 post-mortem: v2 (128 rows/block) regressed via VGPR 60->108 occupancy loss. v3 returns to
// the proven 64-row/60-VGPR structure and instead deletes the staging: per-chunk code working set is
// 8 KB (L1-fits; per-grp slice 256 KB is L2-resident, shared by 250 blocks). B-fragments are read
// directly from g_ebh/g_ebl at the SAME addresses the LDS copy held -> numerics, candidate order,
// and tie-breaks identical. cnt init made per-wave -> no __syncthreads anywhere. LDS 27->8.5 KB.
__global__ void __launch_bounds__(256) k_vq1(){
  __shared__ float2 ring[64][16];
  __shared__ int cnt[64];
  int tid = threadIdx.x, lane = tid & 63, w = tid >> 6;
  int q = lane >> 4, col = lane & 15;
  int rowbase = blockIdx.x * 64 + w * 16;
  int cbase = blockIdx.y * 1024;
  int grp = blockIdx.y;
  if (lane < 16) cnt[w * 16 + lane] = 0;
  #pragma unroll
  for (int i = 0; i < 4; i++)
    ring[w * 16 + (lane & 15)][(lane >> 4) * 4 + i] = make_float2(FLT_MAX, __int_as_float(NE - 1));
  bf16x8 ah0, ah1, al0, al1;
  {
    const unsigned short* zh = g_zbh + (rowbase + col) * 64;
    const unsigned short* zl = g_zbl + (rowbase + col) * 64;
    ah0 = *(const bf16x8*)(zh + q * 8);
    ah1 = *(const bf16x8*)(zh + 32 + q * 8);
    al0 = *(const bf16x8*)(zl + q * 8);
    al1 = *(const bf16x8*)(zl + 32 + q * 8);
  }
  float z2r[4];
  #pragma unroll
  for (int r = 0; r < 4; r++) z2r[r] = g_z2[rowbase + q * 4 + r];
  float thr[4], lmin[4]; int lamc[4];
  #pragma unroll
  for (int r = 0; r < 4; r++){ thr[r] = FLT_MAX; lmin[r] = FLT_MAX; lamc[r] = NE - 1; }
  float runmin[4] = {FLT_MAX, FLT_MAX, FLT_MAX, FLT_MAX};
  for (int ch = 0; ch < 16; ++ch){
    float d2s[4][4];
    float tmin[4] = {FLT_MAX, FLT_MAX, FLT_MAX, FLT_MAX};
    #pragma unroll
    for (int t = 0; t < 4; t++){
      int ct = cbase + ch * 64 + t * 16;
      const unsigned short* bh = g_ebh + (ct + col) * 64;
      const unsigned short* bl = g_ebl + (ct + col) * 64;
      bf16x8 bh0 = *(const bf16x8*)(bh + q * 8);
      bf16x8 bh1 = *(const bf16x8*)(bh + 32 + q * 8);
      bf16x8 bl0 = *(const bf16x8*)(bl + q * 8);
      bf16x8 bl1 = *(const bf16x8*)(bl + 32 + q * 8);
      f32x4 acc = {0.f, 0.f, 0.f, 0.f};
      acc = __builtin_amdgcn_mfma_f32_16x16x32_bf16(al0, bh0, acc, 0, 0, 0);
      acc = __builtin_amdgcn_mfma_f32_16x16x32_bf16(al1, bh1, acc, 0, 0, 0);
      acc = __builtin_amdgcn_mfma_f32_16x16x32_bf16(ah0, bl0, acc, 0, 0, 0);
      acc = __builtin_amdgcn_mfma_f32_16x16x32_bf16(ah1, bl1, acc, 0, 0, 0);
      acc = __builtin_amdgcn_mfma_f32_16x16x32_bf16(ah0, bh0, acc, 0, 0, 0);
      acc = __builtin_amdgcn_mfma_f32_16x16x32_bf16(ah1, bh1, acc, 0, 0, 0);
      float e2c = g_e2[ct + col];
      #pragma unroll
      for (int r = 0; r < 4; r++){
        float d = z2r[r] + e2c - 2.f * acc[r];
        d2s[t][r] = d;
        if (d < lmin[r]){ lmin[r] = d; lamc[r] = ct + col; }
        tmin[r] = fminf(tmin[r], d);
      }
    }
    #pragma unroll
    for (int r = 0; r < 4; r++){
      float m = tmin[r];
      m = fminf(m, __shfl_xor(m, 1, 64));
      m = fminf(m, __shfl_xor(m, 2, 64));
      m = fminf(m, __shfl_xor(m, 4, 64));
      m = fminf(m, __shfl_xor(m, 8, 64));
      if (m < runmin[r]){
        runmin[r] = m;
        thr[r] = m + 0.71f * sqrtf(fmaxf(m, 0.f)) + 0.13f;
      }
    }
    #pragma unroll
    for (int t = 0; t < 4; t++){
      int ct = cbase + ch * 64 + t * 16;
      bool any = false;
      #pragma unroll
      for (int r = 0; r < 4; r++) if (d2s[t][r] < thr[r]) any = true;
      if (__ballot(any)){
        #pragma unroll
        for (int r = 0; r < 4; r++){
          if (d2s[t][r] < thr[r]){
            int lr = w * 16 + q * 4 + r;
            int s = atomicAdd(&cnt[lr], 1) & 15;
            ring[lr][s] = make_float2(sqrtf(fmaxf(d2s[t][r], 1e-12f)), __int_as_float(ct + col));
          }
        }
      }
    }
  }
  #pragma unroll
  for (int r = 0; r < 4; r++){
    float m = lmin[r]; int c = lamc[r];
    #pragma unroll
    for (int o = 1; o <= 8; o <<= 1){
      float om = __shfl_xor(m, o, 64);
      int oc = __shfl_xor(c, o, 64);
      if (om < m || (om == m && oc < c)){ m = om; c = oc; }
    }
    if (col == 0){
      int gr = rowbase + q * 4 + r;
      g_pmd[gr * NCG + grp] = m;
      g_pmi[gr * NCG + grp] = c;
    }
  }
  if (lane < 16){
    int lr = w * 16 + lane;
    g_pcc[(rowbase + lane) * NCG + grp] = cnt[lr];
  }
  #pragma unroll
  for (int i = 0; i < 4; i++){
    int idx = lane * 4 + i;
    int lr = idx >> 4, s = idx & 15;
    g_cand[(rowbase + lr) * 256 + grp * 16 + s] = ring[w * 16 + lr][s];
  }
}

__global__ void k_vq1b(){
  int row = blockIdx.x * 256 + threadIdx.x;
  if (row >= ROWS) return;
  float best = FLT_MAX; int bi = NE - 1;
  for (int cg = 0; cg < NCG; ++cg){
    float d = g_pmd[row * NCG + cg]; int i = g_pmi[row * NCG + cg];
    if (d < best || (d == best && i < bi)){ best = d; bi = i; }
  }
  g_rdm[row] = sqrtf(fmaxf(best, 1e-12f));
  g_rix[row] = bi;
}

// ---------------- VQ pass 3: wave-cooperative f64 re-rank + block-level commit atomic ----------------
__global__ void __launch_bounds__(256) k_vq3(const float* __restrict__ embed,
                                             float* __restrict__ outIdx){
  __shared__ int   ccode[4][144];
  __shared__ float cdst[4][144];
  __shared__ int   cn[4];
  __shared__ double bsum[4];
  int w = threadIdx.x >> 6, lane = threadIdx.x & 63;
  int row = blockIdx.x * 4 + w;
  float dmin = g_rdm[row];
  int seedc = clampc(g_rix[row]);
  if (lane == 0){ cn[w] = 0; ccode[w][0] = seedc; }
  __syncthreads();
  if (lane == 0) cn[w] = 1;
  int grp = lane & 7;
  int sub = lane >> 3;
  int cnt = g_pcc[row * NCG + grp]; if (cnt > 16) cnt = 16;
  int s0 = sub * 2, s1 = s0 + 2; if (s1 > cnt) s1 = cnt;
  for (int s = s0; s < s1; ++s){
    float2 cd = g_cand[row * 256 + grp * 16 + s];
    float dist = cd.x; int c = clampc(__float_as_int(cd.y));
    if (dist <= dmin + 0.353f && c != seedc){
      int i = atomicAdd(&cn[w], 1);
      ccode[w][i] = c;
    }
  }
  __syncthreads();
  int n = cn[w];
  double zdl = g_zbnd[row * 64 + lane];
  double bd = DBL_MAX; int bc = NE - 1;
  for (int i = 0; i < n; i++){
    int c = ccode[w][i];
    double diff = zdl - (double)embed[c * 64 + lane];
    double d = diff * diff;
    #pragma unroll
    for (int o = 32; o; o >>= 1) d += __shfl_xor(d, o, 64);
    if (lane == 0) cdst[w][i] = (float)d;
    if (d < bd || (d == bd && c < bc)){ bd = d; bc = c; }
  }
  __syncthreads();
  float dminE = (float)sqrt(bd);
  float Zp = 0.f;
  for (int i = lane; i < n; i += 64)
    Zp += expf(-100.f * (sqrtf(cdst[w][i]) - dminE));
  float Z = fmaxf(wsum(Zp), 1e-30f);
  if (lane == 0){
    g_rix[row] = bc;
    outIdx[row] = (float)bc;
    bsum[w] = bd;
  }
  for (int i = lane; i < n; i += 64)
    atomicAdd(&g_avg[ccode[w][i]], expf(-100.f * (sqrtf(cdst[w][i]) - dminE)) / Z);
  __syncthreads();
  if (threadIdx.x == 0)
    atomicAdd(&g_misc[0], bsum[0] + bsum[1] + bsum[2] + bsum[3]);
}

__global__ void k_orthoprep(const float* __restrict__ embed, const int* __restrict__ oidx){
  int tid = threadIdx.x;
  int c = clampc(oidx[tid]);
  float s = 0.f;
  for (int j = 0; j < 64; j++){ float v = embed[c * 64 + j]; s += v * v; }
  float r = 1.f / sqrtf(s + 1e-12f);
  for (int j = 0; j < 64; j++) g_ob[tid * 64 + j] = embed[c * 64 + j] * r;
}

__global__ void k_ortho(){
  int w = threadIdx.x >> 6, lane = threadIdx.x & 63;
  int i = blockIdx.x * 4 + w;
  float acc = 0.f;
  for (int j = lane; j < 256; j += 64){
    float d = 0.f;
    for (int k = 0; k < 64; k++) d += g_ob[i * 64 + k] * g_ob[j * 64 + k];
    acc += d * d;
  }
  acc = wsum(acc);
  if (lane == 0) atomicAdd(&g_misc[1], (double)acc);
}

__global__ void k_div(float* __restrict__ outS){
  int tid = threadIdx.x;
  double part = 0.0;
  for (int c = tid; c < NE; c += 256){
    double p = (double)g_avg[c] / 16000.0;
    double pc = p < 1e-30 ? 1e-30 : p;
    part += p * log(pc);
  }
  __shared__ double red[256];
  red[tid] = part; __syncthreads();
  for (int o = 128; o; o >>= 1){ if (tid < o) red[tid] += red[tid + o]; __syncthreads(); }
  if (tid == 0){
    double diversity = red[0];
    double commit = g_misc[0] / (double)(ROWS * 64);
    double ortho = g_misc[1] / 65536.0 - 1.0 / 256.0;
    double loss = commit + diversity + ortho;
    outS[0] = (float)loss;
    outS[1] = (float)commit;
    outS[2] = (float)diversity;
    outS[3] = (float)ortho;
  }
}

__global__ void k_zq(const float* __restrict__ embed){
  __shared__ float tile[64][65];
  int tid = threadIdx.x, b = blockIdx.y, n0 = blockIdx.x * 64;
  for (int i = tid; i < 64 * 64; i += 256){
    int nn = i >> 6, c = i & 63;
    int n = n0 + nn;
    int code = (n < NZ) ? clampc(g_rix[b * NZ + n]) : 0;
    tile[c][nn] = embed[code * 64 + c];
  }
  __syncthreads();
  for (int i = tid; i < 64 * 64; i += 256){
    int c = i >> 6, nn = i & 63;
    int n = n0 + nn;
    if (n < NZ) g_zq[(b * 64 + c) * NZ + n] = tile[c][nn];
  }
}

__global__ void k_folddw1(const float* __restrict__ dw1){
  int gt = blockIdx.x * 256 + threadIdx.x;
  for (int i = gt; i < 64 * 64 * 25; i += 100 * 256){
    int co = i & 63, r = i >> 6, k = r % 25, ci = r / 25;
    g_dw1t[i] = dw1[(ci * 64 + co) * 25 + (24 - k)];
  }
}

// ---------------- dconv1: 4 n/lane weight-amortized, vectorized LDS (b128) reads ----------------
__global__ void __launch_bounds__(256, 3) k_dconv1(){
  __shared__ float xsd[16][260];
  __shared__ float wsh[4][64][28];
  __shared__ float sacc[4], qacc[4];
  int tid = threadIdx.x, b = blockIdx.y;
  int cb = blockIdx.z * 4;
  int t0 = blockIdx.x * 3072;
  int nb = blockIdx.x * 256 - 1;
  int w = tid >> 6, lane = tid & 63;
  if (tid < 4){ sacc[tid] = 0.f; qacc[tid] = 0.f; }
  for (int i = tid; i < 6400; i += 256){
    int c = i & 3, r = i >> 2;
    int k = r % 25, ci = r / 25;
    wsh[c][ci][k] = g_dw1t[r * 64 + cb + c];
  }
  float acc[4][12];
  #pragma unroll
  for (int q = 0; q < 4; q++)
    #pragma unroll
    for (int p = 0; p < 12; p++) acc[q][p] = 0.f;
  for (int cc = 0; cc < 4; ++cc){
    __syncthreads();
    for (int i = tid; i < 16 * 259; i += 256){
      int ci = i / 259, nl = i - ci * 259;
      int n = nb + nl;
      xsd[ci][nl] = ((unsigned)n < NZ) ? g_zq[(b * 64 + cc * 16 + ci) * NZ + n] : 0.f;
    }
    __syncthreads();
    #pragma unroll 2
    for (int ci = 0; ci < 16; ++ci){
      int cia = cc * 16 + ci;
      const float4* xp = (const float4*)&xsd[ci][4 * lane];
      float4 xA = xp[0], xB = xp[1];
      float xv[6] = { xA.x, xA.y, xA.z, xA.w, xB.x, xB.y };
      const float4* wp = (const float4*)&wsh[w][cia][0];
      float4 w0 = wp[0], w1 = wp[1], w2 = wp[2], w3 = wp[3], w4 = wp[4], w5 = wp[5];
      float wv[25] = { w0.x, w0.y, w0.z, w0.w, w1.x, w1.y, w1.z, w1.w,
                       w2.x, w2.y, w2.z, w2.w, w3.x, w3.y, w3.z, w3.w,
                       w4.x, w4.y, w4.z, w4.w, w5.x, w5.y, w5.z, w5.w,
                       wsh[w][cia][24] };
      #pragma unroll
      for (int q = 0; q < 4; ++q){
        acc[q][0] += wv[0] * xv[q];
        acc[q][0] += wv[12] * xv[q + 1];
        acc[q][0] += wv[24] * xv[q + 2];
        #pragma unroll
        for (int p = 1; p < 12; ++p){
          acc[q][p] += wv[12 - p] * xv[q + 1];
          acc[q][p] += wv[24 - p] * xv[q + 2];
        }
      }
    }
  }
  bool full = (t0 + 3072 <= TD);
  float s = 0.f, qs = 0.f;
  float* dst = &g_yd1[(b * 64 + cb + w) * TD + t0 + lane * 48];
  #pragma unroll
  for (int q = 0; q < 4; ++q){
    float o[12];
    #pragma unroll
    for (int p = 0; p < 12; ++p){
      int t = t0 + lane * 48 + q * 12 + p;
      float a = acc[q][p];
      float v = (t < TD) ? a / (1.f + expf(-a)) : 0.f;
      o[p] = v; s += v; qs += v * v;
    }
    if (full){
      ((float4*)(dst + q * 12))[0] = make_float4(o[0], o[1], o[2], o[3]);
      ((float4*)(dst + q * 12))[1] = make_float4(o[4], o[5], o[6], o[7]);
      ((float4*)(dst + q * 12))[2] = make_float4(o[8], o[9], o[10], o[11]);
    } else {
      #pragma unroll
      for (int p = 0; p < 12; ++p){
        int t = t0 + lane * 48 + q * 12 + p;
        if (t < TD) dst[q * 12 + p] = o[p];
      }
    }
  }
  s = wsum(s); qs = wsum(qs);
  if (lane == 0){ atomicAdd(&sacc[w], s); atomicAdd(&qacc[w], qs); }
  __syncthreads();
  if (tid < 4){
    atomicAdd(&g_st[384 + (cb + tid) * 2], (double)sacc[tid]);
    atomicAdd(&g_st[384 + (cb + tid) * 2 + 1], (double)qacc[tid]);
  }
}

// ---------------- bn_d1 factors + dconv2 weight bf16-split fragment prep ----------------
__global__ void k_foldd2(const float* __restrict__ dg1, const float* __restrict__ dbe1,
                         const float* __restrict__ dw2, const float* __restrict__ db2){
  int tid = threadIdx.x;
  if (blockIdx.x == 0 && tid < 64){
    double m = g_st[384 + tid * 2] / 191912.0, v = g_st[384 + tid * 2 + 1] / 191912.0 - m * m;
    float sc = dg1[tid] / sqrtf((float)v + 1e-5f);
    g_sd1[tid] = sc; g_shd1[tid] = dbe1[tid] - (float)m * sc;
    g_db2f[tid] = db2[tid];
  }
  // W fragment layout: idx = ((k*2+c)*64 + co)*32 + ciL ; value = dw2[(co*64 + c*32+ciL)*5 + k]
  int gt = blockIdx.x * 256 + tid;
  for (int i = gt; i < 20480; i += 32 * 256){
    int ciL = i & 31;
    int r = i >> 5;
    int co = r & 63;
    int r2 = r >> 6;
    int c = r2 & 1, k = r2 >> 1;
    float w = dw2[(co * 64 + c * 32 + ciL) * 5 + k];
    unsigned short h = f2bs(w);
    g_dwh[i] = h;
    g_dwl[i] = f2bs(w - bss(h));
  }
}

// ---------------- dconv2 v6: split-bf16 MFMA, t-tile 128, NO in-kernel stats ----------------
__global__ void __launch_bounds__(256, 2) k_dconv2(){
  __shared__ unsigned short xh[132 * 64];   // 16.5 KB, rows gl=0..131, 64 ci, st-swizzled
  __shared__ unsigned short xl[132 * 64];
  __shared__ float sdl[64], shdl[64], bsl2[64];
  int tid = threadIdx.x, b = blockIdx.y;
  int t0 = blockIdx.x * 128;
  int lane = tid & 63, wv = tid >> 6;
  int q = lane >> 4, tcol = lane & 15;
  int cobase = wv * 16;
  if (tid < 64){ sdl[tid] = g_sd1[tid]; shdl[tid] = g_shd1[tid]; bsl2[tid] = g_db2f[tid]; }

  // weight A-fragments: lane holds W[co=cobase+tcol][ciL=q*8..+8] per (k,c) -- L2-resident
  bf16x8 wh[10], wl[10];
  {
    int co = cobase + tcol;
    #pragma unroll
    for (int kc = 0; kc < 10; ++kc){
      wh[kc] = *(const bf16x8*)(g_dwh + (kc * 64 + co) * 32 + q * 8);
      wl[kc] = *(const bf16x8*)(g_dwl + (kc * 64 + co) * 32 + q * 8);
    }
  }
  __syncthreads();

  // stage X^T [gl][ci]: BN + bf16 split; i -> (ci, gl) with consecutive tid = consecutive gl
  // (coalesced global reads along t); swizzle byte = gl*128 + ((ci*2) ^ ((gl&7)<<4)).
  for (int it = 0; it < 33; ++it){                  // 33*256 == 132*64 exactly
    int i = tid + it * 256;
    int ci = (int)((unsigned)i / 132u);
    int gl = i - ci * 132;
    int g = t0 - 2 + gl;
    float val = ((unsigned)g < TD) ? (sdl[ci] * g_yd1[(size_t)(b * 64 + ci) * TD + g] + shdl[ci]) : 0.f;
    unsigned short h = f2bs(val);
    unsigned short lo = f2bs(val - bss(h));
    int off = gl * 128 + ((ci * 2) ^ ((gl & 7) << 4));
    *(unsigned short*)((char*)xh + off) = h;
    *(unsigned short*)((char*)xl + off) = lo;
  }
  __syncthreads();

  // MFMA: 8 t-subtiles x 10 (k,c) x 3 split products = 240 MFMA/wave
  f32x4 acc[8];
  #pragma unroll
  for (int ts = 0; ts < 8; ++ts)
    #pragma unroll
    for (int r = 0; r < 4; ++r) acc[ts][r] = bsl2[cobase + q * 4 + r];
  #pragma unroll
  for (int k = 0; k < 5; ++k){
    #pragma unroll
    for (int c = 0; c < 2; ++c){
      int kc = k * 2 + c;
      #pragma unroll
      for (int ts = 0; ts < 8; ++ts){
        int gl = k + tcol + ts * 16;
        int off = gl * 128 + ((c * 64 + q * 16) ^ ((gl & 7) << 4));
        bf16x8 xhv = *(const bf16x8*)((const char*)xh + off);
        bf16x8 xlv = *(const bf16x8*)((const char*)xl + off);
        acc[ts] = __builtin_amdgcn_mfma_f32_16x16x32_bf16(wh[kc], xlv, acc[ts], 0, 0, 0);
        acc[ts] = __builtin_amdgcn_mfma_f32_16x16x32_bf16(wl[kc], xhv, acc[ts], 0, 0, 0);
        acc[ts] = __builtin_amdgcn_mfma_f32_16x16x32_bf16(wh[kc], xhv, acc[ts], 0, 0, 0);
      }
    }
  }

  // epilogue: silu + store only (stats in separate k_stats pass)
  bool full = (t0 + 128 <= TD);
  #pragma unroll
  for (int r = 0; r < 4; ++r){
    int co = cobase + q * 4 + r;
    float* dst = &g_yd2[(size_t)(b * 64 + co) * TD];
    #pragma unroll
    for (int ts = 0; ts < 8; ++ts){
      int t = t0 + ts * 16 + tcol;
      float a = acc[ts][r];
      if (full || t < TD) dst[t] = a / (1.f + expf(-a));
    }
  }
}

// ---------------- recon ----------------
__global__ void k_recon(const float* __restrict__ dg2, const float* __restrict__ dbe2,
                        const float* __restrict__ dw3, const float* __restrict__ db3,
                        float* __restrict__ outR){
  __shared__ float wf[64];
  __shared__ float bsh2;
  int tid = threadIdx.x, b = blockIdx.y, t0 = blockIdx.x * 256;
  if (tid < 64){
    double m = g_st[512 + tid * 2] / 191912.0, v = g_st[512 + tid * 2 + 1] / 191912.0 - m * m;
    float sc = dg2[tid] / sqrtf((float)v + 1e-5f);
    float shv = dbe2[tid] - (float)m * sc;
    wf[tid] = dw3[tid] * sc;
    float contrib = wsum(dw3[tid] * shv);
    if (tid == 0) bsh2 = db3[0] + contrib;
  }
  __syncthreads();
  int t = t0 + tid;
  if (t < TT){
    if (t < TD){
      float a = bsh2;
      for (int ci = 0; ci < 64; ci++) a += wf[ci] * g_yd2[(b * 64 + ci) * TD + t];
      outR[b * TT + t] = a;
    } else {
      outR[b * TT + t] = 0.f;
    }
  }
}

// ---------------- launch ----------------
extern "C" void kernel_launch(void* const* d_in, const int* in_sizes, int n_in,
                              void* d_out, int out_size, void* d_ws, size_t ws_size,
                              hipStream_t stream){
  (void)in_sizes; (void)n_in; (void)out_size; (void)d_ws; (void)ws_size;
  const float* x    = (const float*)d_in[0];
  const float* w1   = (const float*)d_in[1];
  const float* b1   = (const float*)d_in[2];
  const float* g1   = (const float*)d_in[3];
  const float* be1  = (const float*)d_in[4];
  const float* w2   = (const float*)d_in[5];
  const float* b2   = (const float*)d_in[6];
  const float* g2   = (const float*)d_in[7];
  const float* be2  = (const float*)d_in[8];
  const float* w3   = (const float*)d_in[9];
  const float* b3   = (const float*)d_in[10];
  const float* g3   = (const float*)d_in[11];
  const float* be3  = (const float*)d_in[12];
  const float* embed= (const float*)d_in[13];
  const float* dw1  = (const float*)d_in[14];
  const float* dg1  = (const float*)d_in[15];
  const float* dbe1 = (const float*)d_in[16];
  const float* dw2  = (const float*)d_in[17];
  const float* db2  = (const float*)d_in[18];
  const float* dg2  = (const float*)d_in[19];
  const float* dbe2 = (const float*)d_in[20];
  const float* dw3  = (const float*)d_in[21];
  const float* db3  = (const float*)d_in[22];
  const int* oidx   = (const int*)d_in[23];

  float* out    = (float*)d_out;
  float* outIdx = out + 192000;
  float* outS   = out + 208000;

  hipLaunchKernelGGL(k_zero, dim3(32), dim3(256), 0, stream);
  hipLaunchKernelGGL(k_embprep, dim3(64), dim3(256), 0, stream, embed);
  hipLaunchKernelGGL(k_conv1, dim3(94, 8), dim3(256), 0, stream, x, w1, b1);
  hipLaunchKernelGGL(k_fold2, dim3(8), dim3(256), 0, stream, g1, be1, w2, b2);
  hipLaunchKernelGGL(k_conv2, dim3(94, 8), dim3(256), 0, stream);
  hipLaunchKernelGGL(k_fold3, dim3(64), dim3(256), 0, stream, g2, be2, w3, b3);
  hipLaunchKernelGGL(k_conv3, dim3(63, 8), dim3(256), 0, stream);
  hipLaunchKernelGGL(k_stats, dim3(8, 64), dim3(256), 0, stream, 0, NZ, 256);
  hipLaunchKernelGGL(k_zbn, dim3(32, 8), dim3(256), 0, stream, g3, be3);
  hipLaunchKernelGGL(k_zsplit, dim3(4000), dim3(256), 0, stream);
  hipLaunchKernelGGL(k_vq1, dim3(250, 8), dim3(256), 0, stream);
  hipLaunchKernelGGL(k_vq1b, dim3(63), dim3(256), 0, stream);
  hipLaunchKernelGGL(k_vq3, dim3(4000), dim3(256), 0, stream, embed, outIdx);
  hipLaunchKernelGGL(k_orthoprep, dim3(1), dim3(256), 0, stream, embed, oidx);
  hipLaunchKernelGGL(k_ortho, dim3(64), dim3(256), 0, stream);
  hipLaunchKernelGGL(k_div, dim3(1), dim3(256), 0, stream, outS);
  hipLaunchKernelGGL(k_zq, dim3(32, 8), dim3(256), 0, stream, embed);
  hipLaunchKernelGGL(k_folddw1, dim3(100), dim3(256), 0, stream, dw1);
  hipLaunchKernelGGL(k_dconv1, dim3(8, 8, 16), dim3(256), 0, stream);
  hipLaunchKernelGGL(k_foldd2, dim3(32), dim3(256), 0, stream, dg1, dbe1, dw2, db2);
  hipLaunchKernelGGL(k_dconv2, dim3(188, 8), dim3(256), 0, stream);
  hipLaunchKernelGGL(k_stats, dim3(94, 64), dim3(256), 0, stream, 2, TD, 512);
  hipLaunchKernelGGL(k_recon, dim3(94, 8), dim3(256), 0, stream, dg2, dbe2, dw3, db3, out);
}

// Round 9
// 807.588 us; speedup vs baseline: 1.1450x; 1.1450x over previous
//
#include <hip/hip_runtime.h>
#include <math.h>
#include <float.h>

#define DEV __device__ __forceinline__

#define BB 8
#define TT 24000
#define TD 23989
#define NZ 2000
#define ROWS 16000
#define NE 8192
#define NCG 8

typedef __attribute__((ext_vector_type(8))) short bf16x8;
typedef __attribute__((ext_vector_type(4))) float f32x4;

// ---------------- static device storage ----------------
__device__ double g_st[640];
__device__ double g_misc[2];
__device__ float  g_e2[NE];
__device__ float  g_avg[NE];
__device__ float  g_z2[ROWS];
__device__ float  g_rdm[ROWS];
__device__ int    g_rix[ROWS];
__device__ float  g_ob[256 * 64];
__device__ float  g_pmd[ROWS * NCG];
__device__ int    g_pmi[ROWS * NCG];
__device__ int    g_pcc[ROWS * NCG];
__device__ float2 g_cand[ROWS * 256];
__device__ unsigned short g_zbh[ROWS * 64], g_zbl[ROWS * 64];
__device__ unsigned short g_ebh[NE * 64],  g_ebl[NE * 64];
__device__ float  g_s1[16], g_sh1[16];
__device__ float  g_s2[32], g_sh2[32];
__device__ float  g_sd1[64], g_shd1[64];
__device__ float  g_w2f[2560];
__device__ float  g_b2f[32];
__device__ float  g_w3f[64 * 32 * 25];
__device__ float  g_b3f[64];
__device__ unsigned short g_dwh[5 * 2 * 64 * 32];   // dconv2 W hi-bf16, MFMA fragment order
__device__ unsigned short g_dwl[5 * 2 * 64 * 32];   // dconv2 W lo-bf16
__device__ float  g_db2f[64];
__device__ float  g_dw1t[64 * 64 * 25];
__device__ float  g_zbn[ROWS * 64];
__device__ double g_zbnd[ROWS * 64];
__device__ float  g_zq[BB * 64 * NZ];
__device__ float  g_y1[BB * 16 * TT];
__device__ float  g_zpre[BB * 64 * NZ];
__device__ float  g_yd1[BB * 64 * TD];
__device__ float  g_y2[BB * 32 * TT];
__device__ float  g_yd2[BB * 64 * TD];

DEV float wsum(float v){
  #pragma unroll
  for (int o = 32; o; o >>= 1) v += __shfl_xor(v, o, 64);
  return v;
}
DEV int clampc(int c){ return c < 0 ? 0 : (c > NE - 1 ? NE - 1 : c); }
DEV float bss(unsigned short s){ union { unsigned u; float f; } v; v.u = ((unsigned)s) << 16; return v.f; }
DEV unsigned short f2bs(float f){
  union { float f; unsigned u; } v; v.f = f;
  unsigned r = (v.u + 0x7FFF + ((v.u >> 16) & 1)) >> 16;
  return (unsigned short)r;
}

__global__ void k_zero(){
  int i = blockIdx.x * 256 + threadIdx.x;
  if (i < 640) g_st[i] = 0.0;
  if (i < 2) g_misc[i] = 0.0;
  if (i < NE) g_avg[i] = 0.f;
}

// ---------------- embed prep: |e|^2 + bf16 split ----------------
__global__ void k_embprep(const float* __restrict__ embed){
  int gt = blockIdx.x * 256 + threadIdx.x;
  int gs = gridDim.x * 256;
  for (int i = gt; i < NE * 64; i += gs){
    float v = embed[i];
    unsigned short h = f2bs(v);
    g_ebh[i] = h;
    g_ebl[i] = f2bs(v - bss(h));
  }
  for (int c = gt; c < NE; c += gs){
    float s = 0.f;
    for (int j = 0; j < 64; j++){ float v = embed[c * 64 + j]; s += v * v; }
    g_e2[c] = s;
  }
}

// ---------------- z bf16 split (after zbn) ----------------
__global__ void k_zsplit(){
  int i = blockIdx.x * 256 + threadIdx.x;
  if (i < ROWS * 64){
    float v = g_zbn[i];
    unsigned short h = f2bs(v);
    g_zbh[i] = h;
    g_zbl[i] = f2bs(v - bss(h));
  }
}

// ---------------- conv1: silu + stats ----------------
__global__ void k_conv1(const float* __restrict__ x, const float* __restrict__ w1,
                        const float* __restrict__ b1){
  int b = blockIdx.y, t0 = blockIdx.x * 256, tid = threadIdx.x;
  __shared__ float xs[260], wl[80], bl[16], sacc[16], qacc[16];
  if (tid < 80) wl[tid] = w1[tid];
  if (tid < 16){ bl[tid] = b1[tid]; sacc[tid] = 0.f; qacc[tid] = 0.f; }
  for (int i = tid; i < 260; i += 256){ int g = t0 - 2 + i; xs[i] = ((unsigned)g < TT) ? x[b * TT + g] : 0.f; }
  __syncthreads();
  int t = t0 + tid;
  bool ok = t < TT;
  float xv[5];
  #pragma unroll
  for (int k = 0; k < 5; k++) xv[k] = xs[tid + k];
  float out[16];
  #pragma unroll
  for (int c = 0; c < 16; c++){
    float a = bl[c];
    #pragma unroll
    for (int k = 0; k < 5; k++) a += wl[c * 5 + k] * xv[k];
    float o = ok ? a / (1.f + expf(-a)) : 0.f;
    out[c] = o;
    if (ok) g_y1[(b * 16 + c) * TT + t] = o;
  }
  int lane = tid & 63;
  #pragma unroll
  for (int c = 0; c < 16; c++){
    float s = wsum(out[c]);
    float q = wsum(out[c] * out[c]);
    if (lane == 0){ atomicAdd(&sacc[c], s); atomicAdd(&qacc[c], q); }
  }
  __syncthreads();
  if (tid < 16){ atomicAdd(&g_st[tid * 2], (double)sacc[tid]); atomicAdd(&g_st[tid * 2 + 1], (double)qacc[tid]); }
}

// ---------------- bn1 factors + raw w2 transpose ----------------
__global__ void k_fold2(const float* __restrict__ g1, const float* __restrict__ be1,
                        const float* __restrict__ w2, const float* __restrict__ b2){
  int tid = threadIdx.x;
  if (blockIdx.x == 0 && tid < 16){
    double m = g_st[tid * 2] / 192000.0, v = g_st[tid * 2 + 1] / 192000.0 - m * m;
    float s = g1[tid] / sqrtf((float)v + 1e-5f);
    g_s1[tid] = s; g_sh1[tid] = be1[tid] - (float)m * s;
  }
  if (blockIdx.x == 0 && tid < 32) g_b2f[tid] = b2[tid];
  int gt = blockIdx.x * 256 + tid;
  for (int i = gt; i < 2560; i += 8 * 256){
    int co = i & 31, r = i >> 5, k = r % 5, ci = r / 5;
    g_w2f[i] = w2[(co * 16 + ci) * 5 + k];
  }
}

// ---------------- conv2: 8co/wave x 4t/lane, BN at stage-in, silu, stats ----------------
__global__ void __launch_bounds__(256) k_conv2(){
  int b = blockIdx.y, t0 = blockIdx.x * 256, tid = threadIdx.x;
  __shared__ float xs[16][260];
  __shared__ float sacc[32], qacc[32];
  __shared__ float s1l[16], sh1l[16];
  int lane = tid & 63, wv = tid >> 6;
  int cb = wv * 8;
  if (tid < 32){ sacc[tid] = 0.f; qacc[tid] = 0.f; }
  if (tid < 16){ s1l[tid] = g_s1[tid]; sh1l[tid] = g_sh1[tid]; }
  __syncthreads();
  for (int i = tid; i < 16 * 260; i += 256){
    int ci = i / 260, tt = i - ci * 260, g = t0 - 2 + tt;
    xs[ci][tt] = ((unsigned)g < TT) ? (s1l[ci] * g_y1[(b * 16 + ci) * TT + g] + sh1l[ci]) : 0.f;
  }
  __syncthreads();
  float acc[4][8];
  #pragma unroll
  for (int j = 0; j < 4; j++)
    #pragma unroll
    for (int i = 0; i < 8; i++) acc[j][i] = g_b2f[cb + i];
  for (int ci = 0; ci < 16; ci++){
    #pragma unroll
    for (int k = 0; k < 5; k++){
      const float4* wp = (const float4*)(g_w2f + (ci * 5 + k) * 32 + cb);
      float4 w0 = wp[0], w1v = wp[1];
      float wr[8] = { w0.x, w0.y, w0.z, w0.w, w1v.x, w1v.y, w1v.z, w1v.w };
      #pragma unroll
      for (int j = 0; j < 4; j++){
        float xv = xs[ci][lane + 64 * j + k];
        #pragma unroll
        for (int i = 0; i < 8; i++) acc[j][i] += wr[i] * xv;
      }
    }
  }
  #pragma unroll
  for (int i = 0; i < 8; i++){
    int co = cb + i;
    float s = 0.f, q = 0.f;
    #pragma unroll
    for (int j = 0; j < 4; j++){
      int t = t0 + lane + 64 * j;
      bool ok = t < TT;
      float a = acc[j][i];
      float o = ok ? a / (1.f + expf(-a)) : 0.f;
      if (ok) g_y2[(b * 32 + co) * TT + t] = o;
      s += o; q += o * o;
    }
    s = wsum(s); q = wsum(q);
    if (lane == 0){ atomicAdd(&sacc[co], s); atomicAdd(&qacc[co], q); }
  }
  __syncthreads();
  if (tid < 32){ atomicAdd(&g_st[128 + tid * 2], (double)sacc[tid]); atomicAdd(&g_st[128 + tid * 2 + 1], (double)qacc[tid]); }
}

// ---------------- bn2 factors + raw w3 transpose ----------------
__global__ void k_fold3(const float* __restrict__ g2, const float* __restrict__ be2,
                        const float* __restrict__ w3, const float* __restrict__ b3){
  int tid = threadIdx.x;
  if (blockIdx.x == 0 && tid < 32){
    double m = g_st[128 + tid * 2] / 192000.0, v = g_st[128 + tid * 2 + 1] / 192000.0 - m * m;
    float s = g2[tid] / sqrtf((float)v + 1e-5f);
    g_s2[tid] = s; g_sh2[tid] = be2[tid] - (float)m * s;
  }
  if (blockIdx.x == 0 && tid >= 64 && tid < 128) g_b3f[tid - 64] = b3[tid - 64];
  int gt = blockIdx.x * 256 + tid;
  for (int i = gt; i < 64 * 32 * 25; i += 64 * 256){
    int co = i & 63, r = i >> 6, k = r % 25, ci = r / 25;
    g_w3f[i] = w3[(co * 32 + ci) * 25 + k];
  }
}

// ---------------- conv3: 16co/wave, lane=(t32,ci-half), shfl reduce, tanh ----------------
__global__ void __launch_bounds__(256) k_conv3(){
  __shared__ float xs[32][400];
  __shared__ float s2l[32], sh2l[32];
  int tid = threadIdx.x, b = blockIdx.y, t0 = blockIdx.x * 32;
  int lane = tid & 63, wv = tid >> 6;
  int cb = wv * 16;
  int tl = lane & 31, h = lane >> 5;
  if (tid < 32){ s2l[tid] = g_s2[tid]; sh2l[tid] = g_sh2[tid]; }
  __syncthreads();
  int p0 = t0 * 12 - 12;
  for (int i = tid; i < 32 * 397; i += 256){
    int ci = i / 397, pp = i - ci * 397, g = p0 + pp;
    xs[ci][pp] = ((unsigned)g < TT) ? (s2l[ci] * g_y2[(b * 32 + ci) * TT + g] + sh2l[ci]) : 0.f;
  }
  __syncthreads();
  float acc[16];
  #pragma unroll
  for (int i = 0; i < 16; i++) acc[i] = 0.f;
  for (int cii = 0; cii < 16; cii++){
    int ci = h * 16 + cii;
    #pragma unroll
    for (int k = 0; k < 25; k++){
      float xv = xs[ci][tl * 12 + k];
      const float4* wp = (const float4*)(g_w3f + (ci * 25 + k) * 64 + cb);
      float4 a0 = wp[0], a1 = wp[1], a2 = wp[2], a3 = wp[3];
      acc[0] += a0.x * xv; acc[1] += a0.y * xv; acc[2] += a0.z * xv; acc[3] += a0.w * xv;
      acc[4] += a1.x * xv; acc[5] += a1.y * xv; acc[6] += a1.z * xv; acc[7] += a1.w * xv;
      acc[8] += a2.x * xv; acc[9] += a2.y * xv; acc[10] += a2.z * xv; acc[11] += a2.w * xv;
      acc[12] += a3.x * xv; acc[13] += a3.y * xv; acc[14] += a3.z * xv; acc[15] += a3.w * xv;
    }
  }
  #pragma unroll
  for (int i = 0; i < 16; i++) acc[i] += __shfl_xor(acc[i], 32, 64);
  int t = t0 + tl;
  if (h == 0 && t < NZ){
    #pragma unroll
    for (int i = 0; i < 16; i++)
      g_zpre[(b * 64 + cb + i) * NZ + t] = tanhf(acc[i] + g_b3f[cb + i]);
  }
}

// ---------------- per-channel stats ----------------
__global__ void k_stats(int which, int L, int stoff){
  const float* p = (which == 0) ? g_zpre : (which == 1) ? g_yd1 : g_yd2;
  int co = blockIdx.y, t0 = blockIdx.x * 256, tid = threadIdx.x;
  int t = t0 + tid;
  float s = 0.f, q = 0.f;
  if (t < L){
    for (int b = 0; b < BB; b++){ float v = p[(b * 64 + co) * L + t]; s += v; q += v * v; }
  }
  s = wsum(s); q = wsum(q);
  __shared__ float sa[4], qa[4];
  int w = tid >> 6, lane = tid & 63;
  if (lane == 0){ sa[w] = s; qa[w] = q; }
  __syncthreads();
  if (tid == 0){
    atomicAdd(&g_st[stoff + co * 2], (double)(sa[0] + sa[1] + sa[2] + sa[3]));
    atomicAdd(&g_st[stoff + co * 2 + 1], (double)(qa[0] + qa[1] + qa[2] + qa[3]));
  }
}

// ---------------- bn3 apply + transpose rows + |z|^2 (+f64 copy) ----------------
__global__ void k_zbn(const float* __restrict__ g3, const float* __restrict__ be3){
  __shared__ float tile[64][65];
  __shared__ float s3[64], sh3[64];
  __shared__ double s3d[64], sh3d[64];
  int tid = threadIdx.x, b = blockIdx.y, n0 = blockIdx.x * 64;
  if (tid < 64){
    double m = g_st[256 + tid * 2] / 16000.0, v = g_st[256 + tid * 2 + 1] / 16000.0 - m * m;
    double sd = (double)g3[tid] / sqrt(v + 1e-5);
    double shd = (double)be3[tid] - m * sd;
    s3d[tid] = sd; sh3d[tid] = shd;
    s3[tid] = (float)sd; sh3[tid] = (float)shd;
  }
  __syncthreads();
  for (int i = tid; i < 64 * 64; i += 256){
    int c = i >> 6, nn = i & 63, n = n0 + nn;
    tile[c][nn] = (n < NZ) ? (s3[c] * g_zpre[(b * 64 + c) * NZ + n] + sh3[c]) : 0.f;
  }
  __syncthreads();
  int lane = tid & 63;
  for (int it = 0; it < 16; ++it){
    int nn = (tid >> 6) + it * 4;
    int n = n0 + nn, c = lane;
    if (n < NZ){
      float v = tile[c][nn];
      int row = b * NZ + n;
      g_zbn[row * 64 + c] = v;
      g_zbnd[row * 64 + c] = s3d[c] * (double)g_zpre[(b * 64 + c) * NZ + n] + sh3d[c];
      float s = wsum(v * v);
      if (lane == 0) g_z2[row] = s;
    }
  }
}

// ---------------- VQ pass 1 (v1, proven 154us): split-bf16 MFMA distance scan, LDS-staged codes ----------------
// Ledger: v1 (LDS-staged, 64 rows, 60 VGPR) = 154us; v2 (128 rows) = 201us (VGPR 108 -> occupancy);
// v3 (no staging) = 274us (L2-latency-bound: VALUBusy 31%, MfmaUtil 7%, all pipes idle).
// v1 is the local optimum: staging loads codes once/block + LDS-broadcasts to 4 waves; the 9.3e6
// "conflict" cycles are mostly the wave64 ds_read_b128 8-way floor (1024B/instr vs 128B/cy port).
__global__ void __launch_bounds__(256) k_vq1(){
  __shared__ unsigned short bsh[64 * 72];
  __shared__ unsigned short bsl[64 * 72];
  __shared__ float2 ring[64][16];
  __shared__ int cnt[64];
  int tid = threadIdx.x, lane = tid & 63, w = tid >> 6;
  int q = lane >> 4, col = lane & 15;
  int rowbase = blockIdx.x * 64 + w * 16;
  int cbase = blockIdx.y * 1024;
  int grp = blockIdx.y;
  if (tid < 64) cnt[tid] = 0;
  #pragma unroll
  for (int i = 0; i < 4; i++)
    ring[w * 16 + (lane & 15)][(lane >> 4) * 4 + i] = make_float2(FLT_MAX, __int_as_float(NE - 1));
  bf16x8 ah0, ah1, al0, al1;
  {
    const unsigned short* zh = g_zbh + (rowbase + col) * 64;
    const unsigned short* zl = g_zbl + (rowbase + col) * 64;
    ah0 = *(const bf16x8*)(zh + q * 8);
    ah1 = *(const bf16x8*)(zh + 32 + q * 8);
    al0 = *(const bf16x8*)(zl + q * 8);
    al1 = *(const bf16x8*)(zl + 32 + q * 8);
  }
  float z2r[4];
  #pragma unroll
  for (int r = 0; r < 4; r++) z2r[r] = g_z2[rowbase + q * 4 + r];
  float thr[4], lmin[4]; int lamc[4];
  #pragma unroll
  for (int r = 0; r < 4; r++){ thr[r] = FLT_MAX; lmin[r] = FLT_MAX; lamc[r] = NE - 1; }
  float runmin[4] = {FLT_MAX, FLT_MAX, FLT_MAX, FLT_MAX};
  for (int ch = 0; ch < 16; ++ch){
    __syncthreads();
    {
      int cl = tid >> 2, seg = tid & 3;
      int cglob = cbase + ch * 64 + cl;
      *(int4*)&bsh[cl * 72 + seg * 16]     = *(const int4*)(g_ebh + cglob * 64 + seg * 16);
      *(int4*)&bsh[cl * 72 + seg * 16 + 8] = *(const int4*)(g_ebh + cglob * 64 + seg * 16 + 8);
      *(int4*)&bsl[cl * 72 + seg * 16]     = *(const int4*)(g_ebl + cglob * 64 + seg * 16);
      *(int4*)&bsl[cl * 72 + seg * 16 + 8] = *(const int4*)(g_ebl + cglob * 64 + seg * 16 + 8);
    }
    __syncthreads();
    float d2s[4][4];
    float tmin[4] = {FLT_MAX, FLT_MAX, FLT_MAX, FLT_MAX};
    #pragma unroll
    for (int t = 0; t < 4; t++){
      int ct = cbase + ch * 64 + t * 16;
      const unsigned short* bhp = &bsh[(t * 16 + col) * 72];
      const unsigned short* blp = &bsl[(t * 16 + col) * 72];
      bf16x8 bh0 = *(const bf16x8*)(bhp + q * 8);
      bf16x8 bh1 = *(const bf16x8*)(bhp + 32 + q * 8);
      bf16x8 bl0 = *(const bf16x8*)(blp + q * 8);
      bf16x8 bl1 = *(const bf16x8*)(blp + 32 + q * 8);
      f32x4 acc = {0.f, 0.f, 0.f, 0.f};
      acc = __builtin_amdgcn_mfma_f32_16x16x32_bf16(al0, bh0, acc, 0, 0, 0);
      acc = __builtin_amdgcn_mfma_f32_16x16x32_bf16(al1, bh1, acc, 0, 0, 0);
      acc = __builtin_amdgcn_mfma_f32_16x16x32_bf16(ah0, bl0, acc, 0, 0, 0);
      acc = __builtin_amdgcn_mfma_f32_16x16x32_bf16(ah1, bl1, acc, 0, 0, 0);
      acc = __builtin_amdgcn_mfma_f32_16x16x32_bf16(ah0, bh0, acc, 0, 0, 0);
      acc = __builtin_amdgcn_mfma_f32_16x16x32_bf16(ah1, bh1, acc, 0, 0, 0);
      float e2c = g_e2[ct + col];
      #pragma unroll
      for (int r = 0; r < 4; r++){
        float d = z2r[r] + e2c - 2.f * acc[r];
        d2s[t][r] = d;
        if (d < lmin[r]){ lmin[r] = d; lamc[r] = ct + col; }
        tmin[r] = fminf(tmin[r], d);
      }
    }
    #pragma unroll
    for (int r = 0; r < 4; r++){
      float m = tmin[r];
      m = fminf(m, __shfl_xor(m, 1, 64));
      m = fminf(m, __shfl_xor(m, 2, 64));
      m = fminf(m, __shfl_xor(m, 4, 64));
      m = fminf(m, __shfl_xor(m, 8, 64));
      if (m < runmin[r]){
        runmin[r] = m;
        thr[r] = m + 0.71f * sqrtf(fmaxf(m, 0.f)) + 0.13f;
      }
    }
    #pragma unroll
    for (int t = 0; t < 4; t++){
      int ct = cbase + ch * 64 + t * 16;
      bool any = false;
      #pragma unroll
      for (int r = 0; r < 4; r++) if (d2s[t][r] < thr[r]) any = true;
      if (__ballot(any)){
        #pragma unroll
        for (int r = 0; r < 4; r++){
          if (d2s[t][r] < thr[r]){
            int lr = w * 16 + q * 4 + r;
            int s = atomicAdd(&cnt[lr], 1) & 15;
            ring[lr][s] = make_float2(sqrtf(fmaxf(d2s[t][r], 1e-12f)), __int_as_float(ct + col));
          }
        }
      }
    }
  }
  __syncthreads();
  #pragma unroll
  for (int r = 0; r < 4; r++){
    float m = lmin[r]; int c = lamc[r];
    #pragma unroll
    for (int o = 1; o <= 8; o <<= 1){
      float om = __shfl_xor(m, o, 64);
      int oc = __shfl_xor(c, o, 64);
      if (om < m || (om == m && oc < c)){ m = om; c = oc; }
    }
    if (col == 0){
      int gr = rowbase + q * 4 + r;
      g_pmd[gr * NCG + grp] = m;
      g_pmi[gr * NCG + grp] = c;
    }
  }
  if (lane < 16){
    int lr = w * 16 + lane;
    g_pcc[(rowbase + lane) * NCG + grp] = cnt[lr];
  }
  #pragma unroll
  for (int i = 0; i < 4; i++){
    int idx = lane * 4 + i;
    int lr = idx >> 4, s = idx & 15;
    g_cand[(rowbase + lr) * 256 + grp * 16 + s] = ring[w * 16 + lr][s];
  }
}

__global__ void k_vq1b(){
  int row = blockIdx.x * 256 + threadIdx.x;
  if (row >= ROWS) return;
  float best = FLT_MAX; int bi = NE - 1;
  for (int cg = 0; cg < NCG; ++cg){
    float d = g_pmd[row * NCG + cg]; int i = g_pmi[row * NCG + cg];
    if (d < best || (d == best && i < bi)){ best = d; bi = i; }
  }
  g_rdm[row] = sqrtf(fmaxf(best, 1e-12f));
  g_rix[row] = bi;
}

// ---------------- VQ pass 3: wave-cooperative f64 re-rank + block-level commit atomic ----------------
__global__ void __launch_bounds__(256) k_vq3(const float* __restrict__ embed,
                                             float* __restrict__ outIdx){
  __shared__ int   ccode[4][144];
  __shared__ float cdst[4][144];
  __shared__ int   cn[4];
  __shared__ double bsum[4];
  int w = threadIdx.x >> 6, lane = threadIdx.x & 63;
  int row = blockIdx.x * 4 + w;
  float dmin = g_rdm[row];
  int seedc = clampc(g_rix[row]);
  if (lane == 0){ cn[w] = 0; ccode[w][0] = seedc; }
  __syncthreads();
  if (lane == 0) cn[w] = 1;
  int grp = lane & 7;
  int sub = lane >> 3;
  int cnt = g_pcc[row * NCG + grp]; if (cnt > 16) cnt = 16;
  int s0 = sub * 2, s1 = s0 + 2; if (s1 > cnt) s1 = cnt;
  for (int s = s0; s < s1; ++s){
    float2 cd = g_cand[row * 256 + grp * 16 + s];
    float dist = cd.x; int c = clampc(__float_as_int(cd.y));
    if (dist <= dmin + 0.353f && c != seedc){
      int i = atomicAdd(&cn[w], 1);
      ccode[w][i] = c;
    }
  }
  __syncthreads();
  int n = cn[w];
  double zdl = g_zbnd[row * 64 + lane];
  double bd = DBL_MAX; int bc = NE - 1;
  for (int i = 0; i < n; i++){
    int c = ccode[w][i];
    double diff = zdl - (double)embed[c * 64 + lane];
    double d = diff * diff;
    #pragma unroll
    for (int o = 32; o; o >>= 1) d += __shfl_xor(d, o, 64);
    if (lane == 0) cdst[w][i] = (float)d;
    if (d < bd || (d == bd && c < bc)){ bd = d; bc = c; }
  }
  __syncthreads();
  float dminE = (float)sqrt(bd);
  float Zp = 0.f;
  for (int i = lane; i < n; i += 64)
    Zp += expf(-100.f * (sqrtf(cdst[w][i]) - dminE));
  float Z = fmaxf(wsum(Zp), 1e-30f);
  if (lane == 0){
    g_rix[row] = bc;
    outIdx[row] = (float)bc;
    bsum[w] = bd;
  }
  for (int i = lane; i < n; i += 64)
    atomicAdd(&g_avg[ccode[w][i]], expf(-100.f * (sqrtf(cdst[w][i]) - dminE)) / Z);
  __syncthreads();
  if (threadIdx.x == 0)
    atomicAdd(&g_misc[0], bsum[0] + bsum[1] + bsum[2] + bsum[3]);
}

__global__ void k_orthoprep(const float* __restrict__ embed, const int* __restrict__ oidx){
  int tid = threadIdx.x;
  int c = clampc(oidx[tid]);
  float s = 0.f;
  for (int j = 0; j < 64; j++){ float v = embed[c * 64 + j]; s += v * v; }
  float r = 1.f / sqrtf(s + 1e-12f);
  for (int j = 0; j < 64; j++) g_ob[tid * 64 + j] = embed[c * 64 + j] * r;
}

__global__ void k_ortho(){
  int w = threadIdx.x >> 6, lane = threadIdx.x & 63;
  int i = blockIdx.x * 4 + w;
  float acc = 0.f;
  for (int j = lane; j < 256; j += 64){
    float d = 0.f;
    for (int k = 0; k < 64; k++) d += g_ob[i * 64 + k] * g_ob[j * 64 + k];
    acc += d * d;
  }
  acc = wsum(acc);
  if (lane == 0) atomicAdd(&g_misc[1], (double)acc);
}

__global__ void k_div(float* __restrict__ outS){
  int tid = threadIdx.x;
  double part = 0.0;
  for (int c = tid; c < NE; c += 256){
    double p = (double)g_avg[c] / 16000.0;
    double pc = p < 1e-30 ? 1e-30 : p;
    part += p * log(pc);
  }
  __shared__ double red[256];
  red[tid] = part; __syncthreads();
  for (int o = 128; o; o >>= 1){ if (tid < o) red[tid] += red[tid + o]; __syncthreads(); }
  if (tid == 0){
    double diversity = red[0];
    double commit = g_misc[0] / (double)(ROWS * 64);
    double ortho = g_misc[1] / 65536.0 - 1.0 / 256.0;
    double loss = commit + diversity + ortho;
    outS[0] = (float)loss;
    outS[1] = (float)commit;
    outS[2] = (float)diversity;
    outS[3] = (float)ortho;
  }
}

__global__ void k_zq(const float* __restrict__ embed){
  __shared__ float tile[64][65];
  int tid = threadIdx.x, b = blockIdx.y, n0 = blockIdx.x * 64;
  for (int i = tid; i < 64 * 64; i += 256){
    int nn = i >> 6, c = i & 63;
    int n = n0 + nn;
    int code = (n < NZ) ? clampc(g_rix[b * NZ + n]) : 0;
    tile[c][nn] = embed[code * 64 + c];
  }
  __syncthreads();
  for (int i = tid; i < 64 * 64; i += 256){
    int c = i >> 6, nn = i & 63;
    int n = n0 + nn;
    if (n < NZ) g_zq[(b * 64 + c) * NZ + n] = tile[c][nn];
  }
}

__global__ void k_folddw1(const float* __restrict__ dw1){
  int gt = blockIdx.x * 256 + threadIdx.x;
  for (int i = gt; i < 64 * 64 * 25; i += 100 * 256){
    int co = i & 63, r = i >> 6, k = r % 25, ci = r / 25;
    g_dw1t[i] = dw1[(ci * 64 + co) * 25 + (24 - k)];
  }
}

// ---------------- dconv1: 4 n/lane weight-amortized, vectorized LDS (b128) reads ----------------
__global__ void __launch_bounds__(256, 3) k_dconv1(){
  __shared__ float xsd[16][260];
  __shared__ float wsh[4][64][28];
  __shared__ float sacc[4], qacc[4];
  int tid = threadIdx.x, b = blockIdx.y;
  int cb = blockIdx.z * 4;
  int t0 = blockIdx.x * 3072;
  int nb = blockIdx.x * 256 - 1;
  int w = tid >> 6, lane = tid & 63;
  if (tid < 4){ sacc[tid] = 0.f; qacc[tid] = 0.f; }
  for (int i = tid; i < 6400; i += 256){
    int c = i & 3, r = i >> 2;
    int k = r % 25, ci = r / 25;
    wsh[c][ci][k] = g_dw1t[r * 64 + cb + c];
  }
  float acc[4][12];
  #pragma unroll
  for (int q = 0; q < 4; q++)
    #pragma unroll
    for (int p = 0; p < 12; p++) acc[q][p] = 0.f;
  for (int cc = 0; cc < 4; ++cc){
    __syncthreads();
    for (int i = tid; i < 16 * 259; i += 256){
      int ci = i / 259, nl = i - ci * 259;
      int n = nb + nl;
      xsd[ci][nl] = ((unsigned)n < NZ) ? g_zq[(b * 64 + cc * 16 + ci) * NZ + n] : 0.f;
    }
    __syncthreads();
    #pragma unroll 2
    for (int ci = 0; ci < 16; ++ci){
      int cia = cc * 16 + ci;
      const float4* xp = (const float4*)&xsd[ci][4 * lane];
      float4 xA = xp[0], xB = xp[1];
      float xv[6] = { xA.x, xA.y, xA.z, xA.w, xB.x, xB.y };
      const float4* wp = (const float4*)&wsh[w][cia][0];
      float4 w0 = wp[0], w1 = wp[1], w2 = wp[2], w3 = wp[3], w4 = wp[4], w5 = wp[5];
      float wv[25] = { w0.x, w0.y, w0.z, w0.w, w1.x, w1.y, w1.z, w1.w,
                       w2.x, w2.y, w2.z, w2.w, w3.x, w3.y, w3.z, w3.w,
                       w4.x, w4.y, w4.z, w4.w, w5.x, w5.y, w5.z, w5.w,
                       wsh[w][cia][24] };
      #pragma unroll
      for (int q = 0; q < 4; ++q){
        acc[q][0] += wv[0] * xv[q];
        acc[q][0] += wv[12] * xv[q + 1];
        acc[q][0] += wv[24] * xv[q + 2];
        #pragma unroll
        for (int p = 1; p < 12; ++p){
          acc[q][p] += wv[12 - p] * xv[q + 1];
          acc[q][p] += wv[24 - p] * xv[q + 2];
        }
      }
    }
  }
  bool full = (t0 + 3072 <= TD);
  float s = 0.f, qs = 0.f;
  float* dst = &g_yd1[(b * 64 + cb + w) * TD + t0 + lane * 48];
  #pragma unroll
  for (int q = 0; q < 4; ++q){
    float o[12];
    #pragma unroll
    for (int p = 0; p < 12; ++p){
      int t = t0 + lane * 48 + q * 12 + p;
      float a = acc[q][p];
      float v = (t < TD) ? a / (1.f + expf(-a)) : 0.f;
      o[p] = v; s += v; qs += v * v;
    }
    if (full){
      ((float4*)(dst + q * 12))[0] = make_float4(o[0], o[1], o[2], o[3]);
      ((float4*)(dst + q * 12))[1] = make_float4(o[4], o[5], o[6], o[7]);
      ((float4*)(dst + q * 12))[2] = make_float4(o[8], o[9], o[10], o[11]);
    } else {
      #pragma unroll
      for (int p = 0; p < 12; ++p){
        int t = t0 + lane * 48 + q * 12 + p;
        if (t < TD) dst[q * 12 + p] = o[p];
      }
    }
  }
  s = wsum(s); qs = wsum(qs);
  if (lane == 0){ atomicAdd(&sacc[w], s); atomicAdd(&qacc[w], qs); }
  __syncthreads();
  if (tid < 4){
    atomicAdd(&g_st[384 + (cb + tid) * 2], (double)sacc[tid]);
    atomicAdd(&g_st[384 + (cb + tid) * 2 + 1], (double)qacc[tid]);
  }
}

// ---------------- bn_d1 factors + dconv2 weight bf16-split fragment prep ----------------
__global__ void k_foldd2(const float* __restrict__ dg1, const float* __restrict__ dbe1,
                         const float* __restrict__ dw2, const float* __restrict__ db2){
  int tid = threadIdx.x;
  if (blockIdx.x == 0 && tid < 64){
    double m = g_st[384 + tid * 2] / 191912.0, v = g_st[384 + tid * 2 + 1] / 191912.0 - m * m;
    float sc = dg1[tid] / sqrtf((float)v + 1e-5f);
    g_sd1[tid] = sc; g_shd1[tid] = dbe1[tid] - (float)m * sc;
    g_db2f[tid] = db2[tid];
  }
  // W fragment layout: idx = ((k*2+c)*64 + co)*32 + ciL ; value = dw2[(co*64 + c*32+ciL)*5 + k]
  int gt = blockIdx.x * 256 + tid;
  for (int i = gt; i < 20480; i += 32 * 256){
    int ciL = i & 31;
    int r = i >> 5;
    int co = r & 63;
    int r2 = r >> 6;
    int c = r2 & 1, k = r2 >> 1;
    float w = dw2[(co * 64 + c * 32 + ciL) * 5 + k];
    unsigned short h = f2bs(w);
    g_dwh[i] = h;
    g_dwl[i] = f2bs(w - bss(h));
  }
}

// ---------------- dconv2 v6: split-bf16 MFMA, t-tile 128, NO in-kernel stats ----------------
__global__ void __launch_bounds__(256, 2) k_dconv2(){
  __shared__ unsigned short xh[132 * 64];   // 16.5 KB, rows gl=0..131, 64 ci, st-swizzled
  __shared__ unsigned short xl[132 * 64];
  __shared__ float sdl[64], shdl[64], bsl2[64];
  int tid = threadIdx.x, b = blockIdx.y;
  int t0 = blockIdx.x * 128;
  int lane = tid & 63, wv = tid >> 6;
  int q = lane >> 4, tcol = lane & 15;
  int cobase = wv * 16;
  if (tid < 64){ sdl[tid] = g_sd1[tid]; shdl[tid] = g_shd1[tid]; bsl2[tid] = g_db2f[tid]; }

  // weight A-fragments: lane holds W[co=cobase+tcol][ciL=q*8..+8] per (k,c) -- L2-resident
  bf16x8 wh[10], wl[10];
  {
    int co = cobase + tcol;
    #pragma unroll
    for (int kc = 0; kc < 10; ++kc){
      wh[kc] = *(const bf16x8*)(g_dwh + (kc * 64 + co) * 32 + q * 8);
      wl[kc] = *(const bf16x8*)(g_dwl + (kc * 64 + co) * 32 + q * 8);
    }
  }
  __syncthreads();

  // stage X^T [gl][ci]: BN + bf16 split; i -> (ci, gl) with consecutive tid = consecutive gl
  // (coalesced global reads along t); swizzle byte = gl*128 + ((ci*2) ^ ((gl&7)<<4)).
  for (int it = 0; it < 33; ++it){                  // 33*256 == 132*64 exactly
    int i = tid + it * 256;
    int ci = (int)((unsigned)i / 132u);
    int gl = i - ci * 132;
    int g = t0 - 2 + gl;
    float val = ((unsigned)g < TD) ? (sdl[ci] * g_yd1[(size_t)(b * 64 + ci) * TD + g] + shdl[ci]) : 0.f;
    unsigned short h = f2bs(val);
    unsigned short lo = f2bs(val - bss(h));
    int off = gl * 128 + ((ci * 2) ^ ((gl & 7) << 4));
    *(unsigned short*)((char*)xh + off) = h;
    *(unsigned short*)((char*)xl + off) = lo;
  }
  __syncthreads();

  // MFMA: 8 t-subtiles x 10 (k,c) x 3 split products = 240 MFMA/wave
  f32x4 acc[8];
  #pragma unroll
  for (int ts = 0; ts < 8; ++ts)
    #pragma unroll
    for (int r = 0; r < 4; ++r) acc[ts][r] = bsl2[cobase + q * 4 + r];
  #pragma unroll
  for (int k = 0; k < 5; ++k){
    #pragma unroll
    for (int c = 0; c < 2; ++c){
      int kc = k * 2 + c;
      #pragma unroll
      for (int ts = 0; ts < 8; ++ts){
        int gl = k + tcol + ts * 16;
        int off = gl * 128 + ((c * 64 + q * 16) ^ ((gl & 7) << 4));
        bf16x8 xhv = *(const bf16x8*)((const char*)xh + off);
        bf16x8 xlv = *(const bf16x8*)((const char*)xl + off);
        acc[ts] = __builtin_amdgcn_mfma_f32_16x16x32_bf16(wh[kc], xlv, acc[ts], 0, 0, 0);
        acc[ts] = __builtin_amdgcn_mfma_f32_16x16x32_bf16(wl[kc], xhv, acc[ts], 0, 0, 0);
        acc[ts] = __builtin_amdgcn_mfma_f32_16x16x32_bf16(wh[kc], xhv, acc[ts], 0, 0, 0);
      }
    }
  }

  // epilogue: silu + store only (stats in separate k_stats pass)
  bool full = (t0 + 128 <= TD);
  #pragma unroll
  for (int r = 0; r < 4; ++r){
    int co = cobase + q * 4 + r;
    float* dst = &g_yd2[(size_t)(b * 64 + co) * TD];
    #pragma unroll
    for (int ts = 0; ts < 8; ++ts){
      int t = t0 + ts * 16 + tcol;
      float a = acc[ts][r];
      if (full || t < TD) dst[t] = a / (1.f + expf(-a));
    }
  }
}

// ---------------- recon ----------------
__global__ void k_recon(const float* __restrict__ dg2, const float* __restrict__ dbe2,
                        const float* __restrict__ dw3, const float* __restrict__ db3,
                        float* __restrict__ outR){
  __shared__ float wf[64];
  __shared__ float bsh2;
  int tid = threadIdx.x, b = blockIdx.y, t0 = blockIdx.x * 256;
  if (tid < 64){
    double m = g_st[512 + tid * 2] / 191912.0, v = g_st[512 + tid * 2 + 1] / 191912.0 - m * m;
    float sc = dg2[tid] / sqrtf((float)v + 1e-5f);
    float shv = dbe2[tid] - (float)m * sc;
    wf[tid] = dw3[tid] * sc;
    float contrib = wsum(dw3[tid] * shv);
    if (tid == 0) bsh2 = db3[0] + contrib;
  }
  __syncthreads();
  int t = t0 + tid;
  if (t < TT){
    if (t < TD){
      float a = bsh2;
      for (int ci = 0; ci < 64; ci++) a += wf[ci] * g_yd2[(b * 64 + ci) * TD + t];
      outR[b * TT + t] = a;
    } else {
      outR[b * TT + t] = 0.f;
    }
  }
}

// ---------------- launch ----------------
extern "C" void kernel_launch(void* const* d_in, const int* in_sizes, int n_in,
                              void* d_out, int out_size, void* d_ws, size_t ws_size,
                              hipStream_t stream){
  (void)in_sizes; (void)n_in; (void)out_size; (void)d_ws; (void)ws_size;
  const float* x    = (const float*)d_in[0];
  const float* w1   = (const float*)d_in[1];
  const float* b1   = (const float*)d_in[2];
  const float* g1   = (const float*)d_in[3];
  const float* be1  = (const float*)d_in[4];
  const float* w2   = (const float*)d_in[5];
  const float* b2   = (const float*)d_in[6];
  const float* g2   = (const float*)d_in[7];
  const float* be2  = (const float*)d_in[8];
  const float* w3   = (const float*)d_in[9];
  const float* b3   = (const float*)d_in[10];
  const float* g3   = (const float*)d_in[11];
  const float* be3  = (const float*)d_in[12];
  const float* embed= (const float*)d_in[13];
  const float* dw1  = (const float*)d_in[14];
  const float* dg1  = (const float*)d_in[15];
  const float* dbe1 = (const float*)d_in[16];
  const float* dw2  = (const float*)d_in[17];
  const float* db2  = (const float*)d_in[18];
  const float* dg2  = (const float*)d_in[19];
  const float* dbe2 = (const float*)d_in[20];
  const float* dw3  = (const float*)d_in[21];
  const float* db3  = (const float*)d_in[22];
  const int* oidx   = (const int*)d_in[23];

  float* out    = (float*)d_out;
  float* outIdx = out + 192000;
  float* outS   = out + 208000;

  hipLaunchKernelGGL(k_zero, dim3(32), dim3(256), 0, stream);
  hipLaunchKernelGGL(k_embprep, dim3(64), dim3(256), 0, stream, embed);
  hipLaunchKernelGGL(k_conv1, dim3(94, 8), dim3(256), 0, stream, x, w1, b1);
  hipLaunchKernelGGL(k_fold2, dim3(8), dim3(256), 0, stream, g1, be1, w2, b2);
  hipLaunchKernelGGL(k_conv2, dim3(94, 8), dim3(256), 0, stream);
  hipLaunchKernelGGL(k_fold3, dim3(64), dim3(256), 0, stream, g2, be2, w3, b3);
  hipLaunchKernelGGL(k_conv3, dim3(63, 8), dim3(256), 0, stream);
  hipLaunchKernelGGL(k_stats, dim3(8, 64), dim3(256), 0, stream, 0, NZ, 256);
  hipLaunchKernelGGL(k_zbn, dim3(32, 8), dim3(256), 0, stream, g3, be3);
  hipLaunchKernelGGL(k_zsplit, dim3(4000), dim3(256), 0, stream);
  hipLaunchKernelGGL(k_vq1, dim3(250, 8), dim3(256), 0, stream);
  hipLaunchKernelGGL(k_vq1b, dim3(63), dim3(256), 0, stream);
  hipLaunchKernelGGL(k_vq3, dim3(4000), dim3(256), 0, stream, embed, outIdx);
  hipLaunchKernelGGL(k_orthoprep, dim3(1), dim3(256), 0, stream, embed, oidx);
  hipLaunchKernelGGL(k_ortho, dim3(64), dim3(256), 0, stream);
  hipLaunchKernelGGL(k_div, dim3(1), dim3(256), 0, stream, outS);
  hipLaunchKernelGGL(k_zq, dim3(32, 8), dim3(256), 0, stream, embed);
  hipLaunchKernelGGL(k_folddw1, dim3(100), dim3(256), 0, stream, dw1);
  hipLaunchKernelGGL(k_dconv1, dim3(8, 8, 16), dim3(256), 0, stream);
  hipLaunchKernelGGL(k_foldd2, dim3(32), dim3(256), 0, stream, dg1, dbe1, dw2, db2);
  hipLaunchKernelGGL(k_dconv2, dim3(188, 8), dim3(256), 0, stream);
  hipLaunchKernelGGL(k_stats, dim3(94, 64), dim3(256), 0, stream, 2, TD, 512);
  hipLaunchKernelGGL(k_recon, dim3(94, 8), dim3(256), 0, stream, dg2, dbe2, dw3, db3, out);
}

// Round 10
// 798.226 us; speedup vs baseline: 1.1584x; 1.0117x over previous
//
#include <hip/hip_runtime.h>
#include <math.h>
#include <float.h>

#define DEV __device__ __forceinline__

#define BB 8
#define TT 24000
#define TD 23989
#define NZ 2000
#define ROWS 16000
#define NE 8192
#define NCG 8

typedef __attribute__((ext_vector_type(8))) short bf16x8;
typedef __attribute__((ext_vector_type(4))) float f32x4;

// ---------------- static device storage ----------------
__device__ double g_st[640];
__device__ double g_misc[2];
__device__ float  g_e2[NE];
__device__ float  g_avg[NE];
__device__ float  g_z2[ROWS];
__device__ int    g_rix[ROWS];
__device__ float  g_ob[256 * 64];
__device__ float  g_pmd[ROWS * NCG];
__device__ int    g_pmi[ROWS * NCG];
__device__ int    g_pcc[ROWS * NCG];
__device__ float2 g_cand[ROWS * 256];
__device__ unsigned short g_zbh[ROWS * 64], g_zbl[ROWS * 64];
__device__ unsigned short g_ebh[NE * 64],  g_ebl[NE * 64];
__device__ float  g_s1[16], g_sh1[16];
__device__ float  g_s2[32], g_sh2[32];
__device__ float  g_sd1[64], g_shd1[64];
__device__ float  g_w2f[2560];
__device__ float  g_b2f[32];
__device__ float  g_w3f[64 * 32 * 25];
__device__ float  g_b3f[64];
__device__ unsigned short g_dwh[5 * 2 * 64 * 32];   // dconv2 W hi-bf16, MFMA fragment order
__device__ unsigned short g_dwl[5 * 2 * 64 * 32];   // dconv2 W lo-bf16
__device__ float  g_db2f[64];
__device__ float  g_dw1t[64 * 64 * 25];
__device__ double g_zbnd[ROWS * 64];
__device__ float  g_zq[BB * 64 * NZ];
__device__ float  g_y1[BB * 16 * TT];
__device__ float  g_zpre[BB * 64 * NZ];
__device__ float  g_yd1[BB * 64 * TD];
__device__ float  g_y2[BB * 32 * TT];
__device__ float  g_yd2[BB * 64 * TD];

DEV float wsum(float v){
  #pragma unroll
  for (int o = 32; o; o >>= 1) v += __shfl_xor(v, o, 64);
  return v;
}
DEV int clampc(int c){ return c < 0 ? 0 : (c > NE - 1 ? NE - 1 : c); }
DEV float bss(unsigned short s){ union { unsigned u; float f; } v; v.u = ((unsigned)s) << 16; return v.f; }
DEV unsigned short f2bs(float f){
  union { float f; unsigned u; } v; v.f = f;
  unsigned r = (v.u + 0x7FFF + ((v.u >> 16) & 1)) >> 16;
  return (unsigned short)r;
}

__global__ void k_zero(){
  int i = blockIdx.x * 256 + threadIdx.x;
  if (i < 640) g_st[i] = 0.0;
  if (i < 2) g_misc[i] = 0.0;
  if (i < NE) g_avg[i] = 0.f;
}

// ---------------- embed prep: |e|^2 + bf16 split ----------------
__global__ void k_embprep(const float* __restrict__ embed){
  int gt = blockIdx.x * 256 + threadIdx.x;
  int gs = gridDim.x * 256;
  for (int i = gt; i < NE * 64; i += gs){
    float v = embed[i];
    unsigned short h = f2bs(v);
    g_ebh[i] = h;
    g_ebl[i] = f2bs(v - bss(h));
  }
  for (int c = gt; c < NE; c += gs){
    float s = 0.f;
    for (int j = 0; j < 64; j++){ float v = embed[c * 64 + j]; s += v * v; }
    g_e2[c] = s;
  }
}

// ---------------- conv1: silu + stats ----------------
__global__ void k_conv1(const float* __restrict__ x, const float* __restrict__ w1,
                        const float* __restrict__ b1){
  int b = blockIdx.y, t0 = blockIdx.x * 256, tid = threadIdx.x;
  __shared__ float xs[260], wl[80], bl[16], sacc[16], qacc[16];
  if (tid < 80) wl[tid] = w1[tid];
  if (tid < 16){ bl[tid] = b1[tid]; sacc[tid] = 0.f; qacc[tid] = 0.f; }
  for (int i = tid; i < 260; i += 256){ int g = t0 - 2 + i; xs[i] = ((unsigned)g < TT) ? x[b * TT + g] : 0.f; }
  __syncthreads();
  int t = t0 + tid;
  bool ok = t < TT;
  float xv[5];
  #pragma unroll
  for (int k = 0; k < 5; k++) xv[k] = xs[tid + k];
  float out[16];
  #pragma unroll
  for (int c = 0; c < 16; c++){
    float a = bl[c];
    #pragma unroll
    for (int k = 0; k < 5; k++) a += wl[c * 5 + k] * xv[k];
    float o = ok ? a / (1.f + expf(-a)) : 0.f;
    out[c] = o;
    if (ok) g_y1[(b * 16 + c) * TT + t] = o;
  }
  int lane = tid & 63;
  #pragma unroll
  for (int c = 0; c < 16; c++){
    float s = wsum(out[c]);
    float q = wsum(out[c] * out[c]);
    if (lane == 0){ atomicAdd(&sacc[c], s); atomicAdd(&qacc[c], q); }
  }
  __syncthreads();
  if (tid < 16){ atomicAdd(&g_st[tid * 2], (double)sacc[tid]); atomicAdd(&g_st[tid * 2 + 1], (double)qacc[tid]); }
}

// ---------------- bn1 factors + raw w2 transpose ----------------
__global__ void k_fold2(const float* __restrict__ g1, const float* __restrict__ be1,
                        const float* __restrict__ w2, const float* __restrict__ b2){
  int tid = threadIdx.x;
  if (blockIdx.x == 0 && tid < 16){
    double m = g_st[tid * 2] / 192000.0, v = g_st[tid * 2 + 1] / 192000.0 - m * m;
    float s = g1[tid] / sqrtf((float)v + 1e-5f);
    g_s1[tid] = s; g_sh1[tid] = be1[tid] - (float)m * s;
  }
  if (blockIdx.x == 0 && tid < 32) g_b2f[tid] = b2[tid];
  int gt = blockIdx.x * 256 + tid;
  for (int i = gt; i < 2560; i += 8 * 256){
    int co = i & 31, r = i >> 5, k = r % 5, ci = r / 5;
    g_w2f[i] = w2[(co * 16 + ci) * 5 + k];
  }
}

// ---------------- conv2: 8co/wave x 4t/lane, BN at stage-in, silu, stats ----------------
__global__ void __launch_bounds__(256) k_conv2(){
  int b = blockIdx.y, t0 = blockIdx.x * 256, tid = threadIdx.x;
  __shared__ float xs[16][260];
  __shared__ float sacc[32], qacc[32];
  __shared__ float s1l[16], sh1l[16];
  int lane = tid & 63, wv = tid >> 6;
  int cb = wv * 8;
  if (tid < 32){ sacc[tid] = 0.f; qacc[tid] = 0.f; }
  if (tid < 16){ s1l[tid] = g_s1[tid]; sh1l[tid] = g_sh1[tid]; }
  __syncthreads();
  for (int i = tid; i < 16 * 260; i += 256){
    int ci = i / 260, tt = i - ci * 260, g = t0 - 2 + tt;
    xs[ci][tt] = ((unsigned)g < TT) ? (s1l[ci] * g_y1[(b * 16 + ci) * TT + g] + sh1l[ci]) : 0.f;
  }
  __syncthreads();
  float acc[4][8];
  #pragma unroll
  for (int j = 0; j < 4; j++)
    #pragma unroll
    for (int i = 0; i < 8; i++) acc[j][i] = g_b2f[cb + i];
  for (int ci = 0; ci < 16; ci++){
    #pragma unroll
    for (int k = 0; k < 5; k++){
      const float4* wp = (const float4*)(g_w2f + (ci * 5 + k) * 32 + cb);
      float4 w0 = wp[0], w1v = wp[1];
      float wr[8] = { w0.x, w0.y, w0.z, w0.w, w1v.x, w1v.y, w1v.z, w1v.w };
      #pragma unroll
      for (int j = 0; j < 4; j++){
        float xv = xs[ci][lane + 64 * j + k];
        #pragma unroll
        for (int i = 0; i < 8; i++) acc[j][i] += wr[i] * xv;
      }
    }
  }
  #pragma unroll
  for (int i = 0; i < 8; i++){
    int co = cb + i;
    float s = 0.f, q = 0.f;
    #pragma unroll
    for (int j = 0; j < 4; j++){
      int t = t0 + lane + 64 * j;
      bool ok = t < TT;
      float a = acc[j][i];
      float o = ok ? a / (1.f + expf(-a)) : 0.f;
      if (ok) g_y2[(b * 32 + co) * TT + t] = o;
      s += o; q += o * o;
    }
    s = wsum(s); q = wsum(q);
    if (lane == 0){ atomicAdd(&sacc[co], s); atomicAdd(&qacc[co], q); }
  }
  __syncthreads();
  if (tid < 32){ atomicAdd(&g_st[128 + tid * 2], (double)sacc[tid]); atomicAdd(&g_st[128 + tid * 2 + 1], (double)qacc[tid]); }
}

// ---------------- bn2 factors + raw w3 transpose ----------------
__global__ void k_fold3(const float* __restrict__ g2, const float* __restrict__ be2,
                        const float* __restrict__ w3, const float* __restrict__ b3){
  int tid = threadIdx.x;
  if (blockIdx.x == 0 && tid < 32){
    double m = g_st[128 + tid * 2] / 192000.0, v = g_st[128 + tid * 2 + 1] / 192000.0 - m * m;
    float s = g2[tid] / sqrtf((float)v + 1e-5f);
    g_s2[tid] = s; g_sh2[tid] = be2[tid] - (float)m * s;
  }
  if (blockIdx.x == 0 && tid >= 64 && tid < 128) g_b3f[tid - 64] = b3[tid - 64];
  int gt = blockIdx.x * 256 + tid;
  for (int i = gt; i < 64 * 32 * 25; i += 64 * 256){
    int co = i & 63, r = i >> 6, k = r % 25, ci = r / 25;
    g_w3f[i] = w3[(co * 32 + ci) * 25 + k];
  }
}

// ---------------- conv3: 16co/wave, lane=(t32,ci-half), shfl reduce, tanh ----------------
__global__ void __launch_bounds__(256) k_conv3(){
  __shared__ float xs[32][400];
  __shared__ float s2l[32], sh2l[32];
  int tid = threadIdx.x, b = blockIdx.y, t0 = blockIdx.x * 32;
  int lane = tid & 63, wv = tid >> 6;
  int cb = wv * 16;
  int tl = lane & 31, h = lane >> 5;
  if (tid < 32){ s2l[tid] = g_s2[tid]; sh2l[tid] = g_sh2[tid]; }
  __syncthreads();
  int p0 = t0 * 12 - 12;
  for (int i = tid; i < 32 * 397; i += 256){
    int ci = i / 397, pp = i - ci * 397, g = p0 + pp;
    xs[ci][pp] = ((unsigned)g < TT) ? (s2l[ci] * g_y2[(b * 32 + ci) * TT + g] + sh2l[ci]) : 0.f;
  }
  __syncthreads();
  float acc[16];
  #pragma unroll
  for (int i = 0; i < 16; i++) acc[i] = 0.f;
  for (int cii = 0; cii < 16; cii++){
    int ci = h * 16 + cii;
    #pragma unroll
    for (int k = 0; k < 25; k++){
      float xv = xs[ci][tl * 12 + k];
      const float4* wp = (const float4*)(g_w3f + (ci * 25 + k) * 64 + cb);
      float4 a0 = wp[0], a1 = wp[1], a2 = wp[2], a3 = wp[3];
      acc[0] += a0.x * xv; acc[1] += a0.y * xv; acc[2] += a0.z * xv; acc[3] += a0.w * xv;
      acc[4] += a1.x * xv; acc[5] += a1.y * xv; acc[6] += a1.z * xv; acc[7] += a1.w * xv;
      acc[8] += a2.x * xv; acc[9] += a2.y * xv; acc[10] += a2.z * xv; acc[11] += a2.w * xv;
      acc[12] += a3.x * xv; acc[13] += a3.y * xv; acc[14] += a3.z * xv; acc[15] += a3.w * xv;
    }
  }
  #pragma unroll
  for (int i = 0; i < 16; i++) acc[i] += __shfl_xor(acc[i], 32, 64);
  int t = t0 + tl;
  if (h == 0 && t < NZ){
    #pragma unroll
    for (int i = 0; i < 16; i++)
      g_zpre[(b * 64 + cb + i) * NZ + t] = tanhf(acc[i] + g_b3f[cb + i]);
  }
}

// ---------------- per-channel stats ----------------
__global__ void k_stats(int which, int L, int stoff){
  const float* p = (which == 0) ? g_zpre : (which == 1) ? g_yd1 : g_yd2;
  int co = blockIdx.y, t0 = blockIdx.x * 256, tid = threadIdx.x;
  int t = t0 + tid;
  float s = 0.f, q = 0.f;
  if (t < L){
    for (int b = 0; b < BB; b++){ float v = p[(b * 64 + co) * L + t]; s += v; q += v * v; }
  }
  s = wsum(s); q = wsum(q);
  __shared__ float sa[4], qa[4];
  int w = tid >> 6, lane = tid & 63;
  if (lane == 0){ sa[w] = s; qa[w] = q; }
  __syncthreads();
  if (tid == 0){
    atomicAdd(&g_st[stoff + co * 2], (double)(sa[0] + sa[1] + sa[2] + sa[3]));
    atomicAdd(&g_st[stoff + co * 2 + 1], (double)(qa[0] + qa[1] + qa[2] + qa[3]));
  }
}

// ---------------- bn3 apply + transpose rows + |z|^2 + f64 copy + FUSED bf16 split ----------------
// Round-10 fusion: k_zsplit deleted. The split values here are f2bs of the SAME float v that
// zsplit recomputed from g_zbn -- byte-identical outputs; g_zbn storage dropped entirely.
__global__ void k_zbn(const float* __restrict__ g3, const float* __restrict__ be3){
  __shared__ float tile[64][65];
  __shared__ float s3[64], sh3[64];
  __shared__ double s3d[64], sh3d[64];
  int tid = threadIdx.x, b = blockIdx.y, n0 = blockIdx.x * 64;
  if (tid < 64){
    double m = g_st[256 + tid * 2] / 16000.0, v = g_st[256 + tid * 2 + 1] / 16000.0 - m * m;
    double sd = (double)g3[tid] / sqrt(v + 1e-5);
    double shd = (double)be3[tid] - m * sd;
    s3d[tid] = sd; sh3d[tid] = shd;
    s3[tid] = (float)sd; sh3[tid] = (float)shd;
  }
  __syncthreads();
  for (int i = tid; i < 64 * 64; i += 256){
    int c = i >> 6, nn = i & 63, n = n0 + nn;
    tile[c][nn] = (n < NZ) ? (s3[c] * g_zpre[(b * 64 + c) * NZ + n] + sh3[c]) : 0.f;
  }
  __syncthreads();
  int lane = tid & 63;
  for (int it = 0; it < 16; ++it){
    int nn = (tid >> 6) + it * 4;
    int n = n0 + nn, c = lane;
    if (n < NZ){
      float v = tile[c][nn];
      int row = b * NZ + n;
      unsigned short h = f2bs(v);
      g_zbh[row * 64 + c] = h;
      g_zbl[row * 64 + c] = f2bs(v - bss(h));
      g_zbnd[row * 64 + c] = s3d[c] * (double)g_zpre[(b * 64 + c) * NZ + n] + sh3d[c];
      float s = wsum(v * v);
      if (lane == 0) g_z2[row] = s;
    }
  }
}

// ---------------- VQ pass 1 (v1, proven 154us): split-bf16 MFMA distance scan, LDS-staged codes ----------------
// Ledger: v1 (LDS-staged, 64 rows, 60 VGPR) = 154us; v2 (128 rows) = 201us (VGPR 108 -> occupancy);
// v3 (no staging) = 274us (L2-latency-bound). v1 is the local optimum; the 9.3e6 "conflict" cycles
// are mostly the wave64 ds_read_b128 8-way floor (1024B/instr vs 128B/cy LDS port).
__global__ void __launch_bounds__(256) k_vq1(){
  __shared__ unsigned short bsh[64 * 72];
  __shared__ unsigned short bsl[64 * 72];
  __shared__ float2 ring[64][16];
  __shared__ int cnt[64];
  int tid = threadIdx.x, lane = tid & 63, w = tid >> 6;
  int q = lane >> 4, col = lane & 15;
  int rowbase = blockIdx.x * 64 + w * 16;
  int cbase = blockIdx.y * 1024;
  int grp = blockIdx.y;
  if (tid < 64) cnt[tid] = 0;
  #pragma unroll
  for (int i = 0; i < 4; i++)
    ring[w * 16 + (lane & 15)][(lane >> 4) * 4 + i] = make_float2(FLT_MAX, __int_as_float(NE - 1));
  bf16x8 ah0, ah1, al0, al1;
  {
    const unsigned short* zh = g_zbh + (rowbase + col) * 64;
    const unsigned short* zl = g_zbl + (rowbase + col) * 64;
    ah0 = *(const bf16x8*)(zh + q * 8);
    ah1 = *(const bf16x8*)(zh + 32 + q * 8);
    al0 = *(const bf16x8*)(zl + q * 8);
    al1 = *(const bf16x8*)(zl + 32 + q * 8);
  }
  float z2r[4];
  #pragma unroll
  for (int r = 0; r < 4; r++) z2r[r] = g_z2[rowbase + q * 4 + r];
  float thr[4], lmin[4]; int lamc[4];
  #pragma unroll
  for (int r = 0; r < 4; r++){ thr[r] = FLT_MAX; lmin[r] = FLT_MAX; lamc[r] = NE - 1; }
  float runmin[4] = {FLT_MAX, FLT_MAX, FLT_MAX, FLT_MAX};
  for (int ch = 0; ch < 16; ++ch){
    __syncthreads();
    {
      int cl = tid >> 2, seg = tid & 3;
      int cglob = cbase + ch * 64 + cl;
      *(int4*)&bsh[cl * 72 + seg * 16]     = *(const int4*)(g_ebh + cglob * 64 + seg * 16);
      *(int4*)&bsh[cl * 72 + seg * 16 + 8] = *(const int4*)(g_ebh + cglob * 64 + seg * 16 + 8);
      *(int4*)&bsl[cl * 72 + seg * 16]     = *(const int4*)(g_ebl + cglob * 64 + seg * 16);
      *(int4*)&bsl[cl * 72 + seg * 16 + 8] = *(const int4*)(g_ebl + cglob * 64 + seg * 16 + 8);
    }
    __syncthreads();
    float d2s[4][4];
    float tmin[4] = {FLT_MAX, FLT_MAX, FLT_MAX, FLT_MAX};
    #pragma unroll
    for (int t = 0; t < 4; t++){
      int ct = cbase + ch * 64 + t * 16;
      const unsigned short* bhp = &bsh[(t * 16 + col) * 72];
      const unsigned short* blp = &bsl[(t * 16 + col) * 72];
      bf16x8 bh0 = *(const bf16x8*)(bhp + q * 8);
      bf16x8 bh1 = *(const bf16x8*)(bhp + 32 + q * 8);
      bf16x8 bl0 = *(const bf16x8*)(blp + q * 8);
      bf16x8 bl1 = *(const bf16x8*)(blp + 32 + q * 8);
      f32x4 acc = {0.f, 0.f, 0.f, 0.f};
      acc = __builtin_amdgcn_mfma_f32_16x16x32_bf16(al0, bh0, acc, 0, 0, 0);
      acc = __builtin_amdgcn_mfma_f32_16x16x32_bf16(al1, bh1, acc, 0, 0, 0);
      acc = __builtin_amdgcn_mfma_f32_16x16x32_bf16(ah0, bl0, acc, 0, 0, 0);
      acc = __builtin_amdgcn_mfma_f32_16x16x32_bf16(ah1, bl1, acc, 0, 0, 0);
      acc = __builtin_amdgcn_mfma_f32_16x16x32_bf16(ah0, bh0, acc, 0, 0, 0);
      acc = __builtin_amdgcn_mfma_f32_16x16x32_bf16(ah1, bh1, acc, 0, 0, 0);
      float e2c = g_e2[ct + col];
      #pragma unroll
      for (int r = 0; r < 4; r++){
        float d = z2r[r] + e2c - 2.f * acc[r];
        d2s[t][r] = d;
        if (d < lmin[r]){ lmin[r] = d; lamc[r] = ct + col; }
        tmin[r] = fminf(tmin[r], d);
      }
    }
    #pragma unroll
    for (int r = 0; r < 4; r++){
      float m = tmin[r];
      m = fminf(m, __shfl_xor(m, 1, 64));
      m = fminf(m, __shfl_xor(m, 2, 64));
      m = fminf(m, __shfl_xor(m, 4, 64));
      m = fminf(m, __shfl_xor(m, 8, 64));
      if (m < runmin[r]){
        runmin[r] = m;
        thr[r] = m + 0.71f * sqrtf(fmaxf(m, 0.f)) + 0.13f;
      }
    }
    #pragma unroll
    for (int t = 0; t < 4; t++){
      int ct = cbase + ch * 64 + t * 16;
      bool any = false;
      #pragma unroll
      for (int r = 0; r < 4; r++) if (d2s[t][r] < thr[r]) any = true;
      if (__ballot(any)){
        #pragma unroll
        for (int r = 0; r < 4; r++){
          if (d2s[t][r] < thr[r]){
            int lr = w * 16 + q * 4 + r;
            int s = atomicAdd(&cnt[lr], 1) & 15;
            ring[lr][s] = make_float2(sqrtf(fmaxf(d2s[t][r], 1e-12f)), __int_as_float(ct + col));
          }
        }
      }
    }
  }
  __syncthreads();
  #pragma unroll
  for (int r = 0; r < 4; r++){
    float m = lmin[r]; int c = lamc[r];
    #pragma unroll
    for (int o = 1; o <= 8; o <<= 1){
      float om = __shfl_xor(m, o, 64);
      int oc = __shfl_xor(c, o, 64);
      if (om < m || (om == m && oc < c)){ m = om; c = oc; }
    }
    if (col == 0){
      int gr = rowbase + q * 4 + r;
      g_pmd[gr * NCG + grp] = m;
      g_pmi[gr * NCG + grp] = c;
    }
  }
  if (lane < 16){
    int lr = w * 16 + lane;
    g_pcc[(rowbase + lane) * NCG + grp] = cnt[lr];
  }
  #pragma unroll
  for (int i = 0; i < 4; i++){
    int idx = lane * 4 + i;
    int lr = idx >> 4, s = idx & 15;
    g_cand[(rowbase + lr) * 256 + grp * 16 + s] = ring[w * 16 + lr][s];
  }
}

// ---------------- VQ pass 3: FUSED vq1b prologue + wave-cooperative f64 re-rank ----------------
// Round-10 fusion: vq1b's 8-group argmin is replicated per wave -- every lane loads (pmd,pmi) at
// cg = lane&7, then xor-1/2/4 reduce with the SAME (d<best || (d==best && i<bi)) rule => every lane
// holds the full 8-way result (identical value & tie-break to the old k_vq1b). g_rdm eliminated.
__global__ void __launch_bounds__(256) k_vq3(const float* __restrict__ embed,
                                             float* __restrict__ outIdx){
  __shared__ int   ccode[4][144];
  __shared__ float cdst[4][144];
  __shared__ int   cn[4];
  __shared__ double bsum[4];
  int w = threadIdx.x >> 6, lane = threadIdx.x & 63;
  int row = blockIdx.x * 4 + w;
  float best = g_pmd[row * NCG + (lane & 7)];
  int   bi   = g_pmi[row * NCG + (lane & 7)];
  #pragma unroll
  for (int o = 1; o <= 4; o <<= 1){
    float om = __shfl_xor(best, o, 64);
    int   oc = __shfl_xor(bi, o, 64);
    if (om < best || (om == best && oc < bi)){ best = om; bi = oc; }
  }
  float dmin = sqrtf(fmaxf(best, 1e-12f));
  int seedc = clampc(bi);
  if (lane == 0){ cn[w] = 0; ccode[w][0] = seedc; }
  __syncthreads();
  if (lane == 0) cn[w] = 1;
  int grp = lane & 7;
  int sub = lane >> 3;
  int cnt = g_pcc[row * NCG + grp]; if (cnt > 16) cnt = 16;
  int s0 = sub * 2, s1 = s0 + 2; if (s1 > cnt) s1 = cnt;
  for (int s = s0; s < s1; ++s){
    float2 cd = g_cand[row * 256 + grp * 16 + s];
    float dist = cd.x; int c = clampc(__float_as_int(cd.y));
    if (dist <= dmin + 0.353f && c != seedc){
      int i = atomicAdd(&cn[w], 1);
      ccode[w][i] = c;
    }
  }
  __syncthreads();
  int n = cn[w];
  double zdl = g_zbnd[row * 64 + lane];
  double bd = DBL_MAX; int bc = NE - 1;
  for (int i = 0; i < n; i++){
    int c = ccode[w][i];
    double diff = zdl - (double)embed[c * 64 + lane];
    double d = diff * diff;
    #pragma unroll
    for (int o = 32; o; o >>= 1) d += __shfl_xor(d, o, 64);
    if (lane == 0) cdst[w][i] = (float)d;
    if (d < bd || (d == bd && c < bc)){ bd = d; bc = c; }
  }
  __syncthreads();
  float dminE = (float)sqrt(bd);
  float Zp = 0.f;
  for (int i = lane; i < n; i += 64)
    Zp += expf(-100.f * (sqrtf(cdst[w][i]) - dminE));
  float Z = fmaxf(wsum(Zp), 1e-30f);
  if (lane == 0){
    g_rix[row] = bc;
    outIdx[row] = (float)bc;
    bsum[w] = bd;
  }
  for (int i = lane; i < n; i += 64)
    atomicAdd(&g_avg[ccode[w][i]], expf(-100.f * (sqrtf(cdst[w][i]) - dminE)) / Z);
  __syncthreads();
  if (threadIdx.x == 0)
    atomicAdd(&g_misc[0], bsum[0] + bsum[1] + bsum[2] + bsum[3]);
}

__global__ void k_orthoprep(const float* __restrict__ embed, const int* __restrict__ oidx){
  int tid = threadIdx.x;
  int c = clampc(oidx[tid]);
  float s = 0.f;
  for (int j = 0; j < 64; j++){ float v = embed[c * 64 + j]; s += v * v; }
  float r = 1.f / sqrtf(s + 1e-12f);
  for (int j = 0; j < 64; j++) g_ob[tid * 64 + j] = embed[c * 64 + j] * r;
}

__global__ void k_ortho(){
  int w = threadIdx.x >> 6, lane = threadIdx.x & 63;
  int i = blockIdx.x * 4 + w;
  float acc = 0.f;
  for (int j = lane; j < 256; j += 64){
    float d = 0.f;
    for (int k = 0; k < 64; k++) d += g_ob[i * 64 + k] * g_ob[j * 64 + k];
    acc += d * d;
  }
  acc = wsum(acc);
  if (lane == 0) atomicAdd(&g_misc[1], (double)acc);
}

__global__ void k_div(float* __restrict__ outS){
  int tid = threadIdx.x;
  double part = 0.0;
  for (int c = tid; c < NE; c += 256){
    double p = (double)g_avg[c] / 16000.0;
    double pc = p < 1e-30 ? 1e-30 : p;
    part += p * log(pc);
  }
  __shared__ double red[256];
  red[tid] = part; __syncthreads();
  for (int o = 128; o; o >>= 1){ if (tid < o) red[tid] += red[tid + o]; __syncthreads(); }
  if (tid == 0){
    double diversity = red[0];
    double commit = g_misc[0] / (double)(ROWS * 64);
    double ortho = g_misc[1] / 65536.0 - 1.0 / 256.0;
    double loss = commit + diversity + ortho;
    outS[0] = (float)loss;
    outS[1] = (float)commit;
    outS[2] = (float)diversity;
    outS[3] = (float)ortho;
  }
}

__global__ void k_zq(const float* __restrict__ embed){
  __shared__ float tile[64][65];
  int tid = threadIdx.x, b = blockIdx.y, n0 = blockIdx.x * 64;
  for (int i = tid; i < 64 * 64; i += 256){
    int nn = i >> 6, c = i & 63;
    int n = n0 + nn;
    int code = (n < NZ) ? clampc(g_rix[b * NZ + n]) : 0;
    tile[c][nn] = embed[code * 64 + c];
  }
  __syncthreads();
  for (int i = tid; i < 64 * 64; i += 256){
    int c = i >> 6, nn = i & 63;
    int n = n0 + nn;
    if (n < NZ) g_zq[(b * 64 + c) * NZ + n] = tile[c][nn];
  }
}

__global__ void k_folddw1(const float* __restrict__ dw1){
  int gt = blockIdx.x * 256 + threadIdx.x;
  for (int i = gt; i < 64 * 64 * 25; i += 100 * 256){
    int co = i & 63, r = i >> 6, k = r % 25, ci = r / 25;
    g_dw1t[i] = dw1[(ci * 64 + co) * 25 + (24 - k)];
  }
}

// ---------------- dconv1: 4 n/lane weight-amortized, vectorized LDS (b128) reads ----------------
__global__ void __launch_bounds__(256, 3) k_dconv1(){
  __shared__ float xsd[16][260];
  __shared__ float wsh[4][64][28];
  __shared__ float sacc[4], qacc[4];
  int tid = threadIdx.x, b = blockIdx.y;
  int cb = blockIdx.z * 4;
  int t0 = blockIdx.x * 3072;
  int nb = blockIdx.x * 256 - 1;
  int w = tid >> 6, lane = tid & 63;
  if (tid < 4){ sacc[tid] = 0.f; qacc[tid] = 0.f; }
  for (int i = tid; i < 6400; i += 256){
    int c = i & 3, r = i >> 2;
    int k = r % 25, ci = r / 25;
    wsh[c][ci][k] = g_dw1t[r * 64 + cb + c];
  }
  float acc[4][12];
  #pragma unroll
  for (int q = 0; q < 4; q++)
    #pragma unroll
    for (int p = 0; p < 12; p++) acc[q][p] = 0.f;
  for (int cc = 0; cc < 4; ++cc){
    __syncthreads();
    for (int i = tid; i < 16 * 259; i += 256){
      int ci = i / 259, nl = i - ci * 259;
      int n = nb + nl;
      xsd[ci][nl] = ((unsigned)n < NZ) ? g_zq[(b * 64 + cc * 16 + ci) * NZ + n] : 0.f;
    }
    __syncthreads();
    #pragma unroll 2
    for (int ci = 0; ci < 16; ++ci){
      int cia = cc * 16 + ci;
      const float4* xp = (const float4*)&xsd[ci][4 * lane];
      float4 xA = xp[0], xB = xp[1];
      float xv[6] = { xA.x, xA.y, xA.z, xA.w, xB.x, xB.y };
      const float4* wp = (const float4*)&wsh[w][cia][0];
      float4 w0 = wp[0], w1 = wp[1], w2 = wp[2], w3 = wp[3], w4 = wp[4], w5 = wp[5];
      float wv[25] = { w0.x, w0.y, w0.z, w0.w, w1.x, w1.y, w1.z, w1.w,
                       w2.x, w2.y, w2.z, w2.w, w3.x, w3.y, w3.z, w3.w,
                       w4.x, w4.y, w4.z, w4.w, w5.x, w5.y, w5.z, w5.w,
                       wsh[w][cia][24] };
      #pragma unroll
      for (int q = 0; q < 4; ++q){
        acc[q][0] += wv[0] * xv[q];
        acc[q][0] += wv[12] * xv[q + 1];
        acc[q][0] += wv[24] * xv[q + 2];
        #pragma unroll
        for (int p = 1; p < 12; ++p){
          acc[q][p] += wv[12 - p] * xv[q + 1];
          acc[q][p] += wv[24 - p] * xv[q + 2];
        }
      }
    }
  }
  bool full = (t0 + 3072 <= TD);
  float s = 0.f, qs = 0.f;
  float* dst = &g_yd1[(b * 64 + cb + w) * TD + t0 + lane * 48];
  #pragma unroll
  for (int q = 0; q < 4; ++q){
    float o[12];
    #pragma unroll
    for (int p = 0; p < 12; ++p){
      int t = t0 + lane * 48 + q * 12 + p;
      float a = acc[q][p];
      float v = (t < TD) ? a / (1.f + expf(-a)) : 0.f;
      o[p] = v; s += v; qs += v * v;
    }
    if (full){
      ((float4*)(dst + q * 12))[0] = make_float4(o[0], o[1], o[2], o[3]);
      ((float4*)(dst + q * 12))[1] = make_float4(o[4], o[5], o[6], o[7]);
      ((float4*)(dst + q * 12))[2] = make_float4(o[8], o[9], o[10], o[11]);
    } else {
      #pragma unroll
      for (int p = 0; p < 12; ++p){
        int t = t0 + lane * 48 + q * 12 + p;
        if (t < TD) dst[q * 12 + p] = o[p];
      }
    }
  }
  s = wsum(s); qs = wsum(qs);
  if (lane == 0){ atomicAdd(&sacc[w], s); atomicAdd(&qacc[w], qs); }
  __syncthreads();
  if (tid < 4){
    atomicAdd(&g_st[384 + (cb + tid) * 2], (double)sacc[tid]);
    atomicAdd(&g_st[384 + (cb + tid) * 2 + 1], (double)qacc[tid]);
  }
}

// ---------------- bn_d1 factors + dconv2 weight bf16-split fragment prep ----------------
__global__ void k_foldd2(const float* __restrict__ dg1, const float* __restrict__ dbe1,
                         const float* __restrict__ dw2, const float* __restrict__ db2){
  int tid = threadIdx.x;
  if (blockIdx.x == 0 && tid < 64){
    double m = g_st[384 + tid * 2] / 191912.0, v = g_st[384 + tid * 2 + 1] / 191912.0 - m * m;
    float sc = dg1[tid] / sqrtf((float)v + 1e-5f);
    g_sd1[tid] = sc; g_shd1[tid] = dbe1[tid] - (float)m * sc;
    g_db2f[tid] = db2[tid];
  }
  // W fragment layout: idx = ((k*2+c)*64 + co)*32 + ciL ; value = dw2[(co*64 + c*32+ciL)*5 + k]
  int gt = blockIdx.x * 256 + tid;
  for (int i = gt; i < 20480; i += 32 * 256){
    int ciL = i & 31;
    int r = i >> 5;
    int co = r & 63;
    int r2 = r >> 6;
    int c = r2 & 1, k = r2 >> 1;
    float w = dw2[(co * 64 + c * 32 + ciL) * 5 + k];
    unsigned short h = f2bs(w);
    g_dwh[i] = h;
    g_dwl[i] = f2bs(w - bss(h));
  }
}

// ---------------- dconv2 v6: split-bf16 MFMA, t-tile 128, NO in-kernel stats ----------------
__global__ void __launch_bounds__(256, 2) k_dconv2(){
  __shared__ unsigned short xh[132 * 64];   // 16.5 KB, rows gl=0..131, 64 ci, st-swizzled
  __shared__ unsigned short xl[132 * 64];
  __shared__ float sdl[64], shdl[64], bsl2[64];
  int tid = threadIdx.x, b = blockIdx.y;
  int t0 = blockIdx.x * 128;
  int lane = tid & 63, wv = tid >> 6;
  int q = lane >> 4, tcol = lane & 15;
  int cobase = wv * 16;
  if (tid < 64){ sdl[tid] = g_sd1[tid]; shdl[tid] = g_shd1[tid]; bsl2[tid] = g_db2f[tid]; }

  // weight A-fragments: lane holds W[co=cobase+tcol][ciL=q*8..+8] per (k,c) -- L2-resident
  bf16x8 wh[10], wl[10];
  {
    int co = cobase + tcol;
    #pragma unroll
    for (int kc = 0; kc < 10; ++kc){
      wh[kc] = *(const bf16x8*)(g_dwh + (kc * 64 + co) * 32 + q * 8);
      wl[kc] = *(const bf16x8*)(g_dwl + (kc * 64 + co) * 32 + q * 8);
    }
  }
  __syncthreads();

  // stage X^T [gl][ci]: BN + bf16 split; i -> (ci, gl) with consecutive tid = consecutive gl
  // (coalesced global reads along t); swizzle byte = gl*128 + ((ci*2) ^ ((gl&7)<<4)).
  for (int it = 0; it < 33; ++it){                  // 33*256 == 132*64 exactly
    int i = tid + it * 256;
    int ci = (int)((unsigned)i / 132u);
    int gl = i - ci * 132;
    int g = t0 - 2 + gl;
    float val = ((unsigned)g < TD) ? (sdl[ci] * g_yd1[(size_t)(b * 64 + ci) * TD + g] + shdl[ci]) : 0.f;
    unsigned short h = f2bs(val);
    unsigned short lo = f2bs(val - bss(h));
    int off = gl * 128 + ((ci * 2) ^ ((gl & 7) << 4));
    *(unsigned short*)((char*)xh + off) = h;
    *(unsigned short*)((char*)xl + off) = lo;
  }
  __syncthreads();

  // MFMA: 8 t-subtiles x 10 (k,c) x 3 split products = 240 MFMA/wave
  f32x4 acc[8];
  #pragma unroll
  for (int ts = 0; ts < 8; ++ts)
    #pragma unroll
    for (int r = 0; r < 4; ++r) acc[ts][r] = bsl2[cobase + q * 4 + r];
  #pragma unroll
  for (int k = 0; k < 5; ++k){
    #pragma unroll
    for (int c = 0; c < 2; ++c){
      int kc = k * 2 + c;
      #pragma unroll
      for (int ts = 0; ts < 8; ++ts){
        int gl = k + tcol + ts * 16;
        int off = gl * 128 + ((c * 64 + q * 16) ^ ((gl & 7) << 4));
        bf16x8 xhv = *(const bf16x8*)((const char*)xh + off);
        bf16x8 xlv = *(const bf16x8*)((const char*)xl + off);
        acc[ts] = __builtin_amdgcn_mfma_f32_16x16x32_bf16(wh[kc], xlv, acc[ts], 0, 0, 0);
        acc[ts] = __builtin_amdgcn_mfma_f32_16x16x32_bf16(wl[kc], xhv, acc[ts], 0, 0, 0);
        acc[ts] = __builtin_amdgcn_mfma_f32_16x16x32_bf16(wh[kc], xhv, acc[ts], 0, 0, 0);
      }
    }
  }

  // epilogue: silu + store only (stats in separate k_stats pass)
  bool full = (t0 + 128 <= TD);
  #pragma unroll
  for (int r = 0; r < 4; ++r){
    int co = cobase + q * 4 + r;
    float* dst = &g_yd2[(size_t)(b * 64 + co) * TD];
    #pragma unroll
    for (int ts = 0; ts < 8; ++ts){
      int t = t0 + ts * 16 + tcol;
      float a = acc[ts][r];
      if (full || t < TD) dst[t] = a / (1.f + expf(-a));
    }
  }
}

// ---------------- recon ----------------
__global__ void k_recon(const float* __restrict__ dg2, const float* __restrict__ dbe2,
                        const float* __restrict__ dw3, const float* __restrict__ db3,
                        float* __restrict__ outR){
  __shared__ float wf[64];
  __shared__ float bsh2;
  int tid = threadIdx.x, b = blockIdx.y, t0 = blockIdx.x * 256;
  if (tid < 64){
    double m = g_st[512 + tid * 2] / 191912.0, v = g_st[512 + tid * 2 + 1] / 191912.0 - m * m;
    float sc = dg2[tid] / sqrtf((float)v + 1e-5f);
    float shv = dbe2[tid] - (float)m * sc;
    wf[tid] = dw3[tid] * sc;
    float contrib = wsum(dw3[tid] * shv);
    if (tid == 0) bsh2 = db3[0] + contrib;
  }
  __syncthreads();
  int t = t0 + tid;
  if (t < TT){
    if (t < TD){
      float a = bsh2;
      for (int ci = 0; ci < 64; ci++) a += wf[ci] * g_yd2[(b * 64 + ci) * TD + t];
      outR[b * TT + t] = a;
    } else {
      outR[b * TT + t] = 0.f;
    }
  }
}

// ---------------- launch ----------------
extern "C" void kernel_launch(void* const* d_in, const int* in_sizes, int n_in,
                              void* d_out, int out_size, void* d_ws, size_t ws_size,
                              hipStream_t stream){
  (void)in_sizes; (void)n_in; (void)out_size; (void)d_ws; (void)ws_size;
  const float* x    = (const float*)d_in[0];
  const float* w1   = (const float*)d_in[1];
  const float* b1   = (const float*)d_in[2];
  const float* g1   = (const float*)d_in[3];
  const float* be1  = (const float*)d_in[4];
  const float* w2   = (const float*)d_in[5];
  const float* b2   = (const float*)d_in[6];
  const float* g2   = (const float*)d_in[7];
  const float* be2  = (const float*)d_in[8];
  const float* w3   = (const float*)d_in[9];
  const float* b3   = (const float*)d_in[10];
  const float* g3   = (const float*)d_in[11];
  const float* be3  = (const float*)d_in[12];
  const float* embed= (const float*)d_in[13];
  const float* dw1  = (const float*)d_in[14];
  const float* dg1  = (const float*)d_in[15];
  const float* dbe1 = (const float*)d_in[16];
  const float* dw2  = (const float*)d_in[17];
  const float* db2  = (const float*)d_in[18];
  const float* dg2  = (const float*)d_in[19];
  const float* dbe2 = (const float*)d_in[20];
  const float* dw3  = (const float*)d_in[21];
  const float* db3  = (const float*)d_in[22];
  const int* oidx   = (const int*)d_in[23];

  float* out    = (float*)d_out;
  float* outIdx = out + 192000;
  float* outS   = out + 208000;

  hipLaunchKernelGGL(k_zero, dim3(32), dim3(256), 0, stream);
  hipLaunchKernelGGL(k_embprep, dim3(64), dim3(256), 0, stream, embed);
  hipLaunchKernelGGL(k_conv1, dim3(94, 8), dim3(256), 0, stream, x, w1, b1);
  hipLaunchKernelGGL(k_fold2, dim3(8), dim3(256), 0, stream, g1, be1, w2, b2);
  hipLaunchKernelGGL(k_conv2, dim3(94, 8), dim3(256), 0, stream);
  hipLaunchKernelGGL(k_fold3, dim3(64), dim3(256), 0, stream, g2, be2, w3, b3);
  hipLaunchKernelGGL(k_conv3, dim3(63, 8), dim3(256), 0, stream);
  hipLaunchKernelGGL(k_stats, dim3(8, 64), dim3(256), 0, stream, 0, NZ, 256);
  hipLaunchKernelGGL(k_zbn, dim3(32, 8), dim3(256), 0, stream, g3, be3);
  hipLaunchKernelGGL(k_vq1, dim3(250, 8), dim3(256), 0, stream);
  hipLaunchKernelGGL(k_vq3, dim3(4000), dim3(256), 0, stream, embed, outIdx);
  hipLaunchKernelGGL(k_orthoprep, dim3(1), dim3(256), 0, stream, embed, oidx);
  hipLaunchKernelGGL(k_ortho, dim3(64), dim3(256), 0, stream);
  hipLaunchKernelGGL(k_div, dim3(1), dim3(256), 0, stream, outS);
  hipLaunchKernelGGL(k_zq, dim3(32, 8), dim3(256), 0, stream, embed);
  hipLaunchKernelGGL(k_folddw1, dim3(100), dim3(256), 0, stream, dw1);
  hipLaunchKernelGGL(k_dconv1, dim3(8, 8, 16), dim3(256), 0, stream);
  hipLaunchKernelGGL(k_foldd2, dim3(32), dim3(256), 0, stream, dg1, dbe1, dw2, db2);
  hipLaunchKernelGGL(k_dconv2, dim3(188, 8), dim3(256), 0, stream);
  hipLaunchKernelGGL(k_stats, dim3(94, 64), dim3(256), 0, stream, 2, TD, 512);
  hipLaunchKernelGGL(k_recon, dim3(94, 8), dim3(256), 0, stream, dg2, dbe2, dw3, db3, out);
}